// Round 5
// baseline (820.953 us; speedup 1.0000x reference)
//
#include <hip/hip_runtime.h>
#include <hip/hip_bf16.h>
#include <stdint.h>

// x: (4,4096,1024) f32 -> 16384 x 1024 rows; codebook: (16384,1024) f32
#define NROWS  16384
#define NCODES 16384
#define DIM    1024
#define NT     16          // DIM / BK,  BK = 64
#define TCH    2048        // 16B chunks per 256x64 tile
// Quantized-key margin: 3.0 (bf16 ~20 sigma) + 2/16 quant slop, in 1/16 units.
#define MARGIN_Q 52

typedef float f32x4  __attribute__((ext_vector_type(4)));
typedef short bf16x8 __attribute__((ext_vector_type(8)));

__device__ __forceinline__ ushort f2bf(float f) {
  uint32_t u = __float_as_uint(f);
  uint32_t r = u + 0x7FFFu + ((u >> 16) & 1u);
  return (ushort)(r >> 16);
}
__device__ __forceinline__ int imin(int a, int b){ return a < b ? a : b; }
__device__ __forceinline__ int imax(int a, int b){ return a < b ? b : a; }
// 32-bit monotone key: q = rint(score*16) in upper 18 bits, code idx in low 14.
__device__ __forceinline__ int packKey32(float s, int idx) {
  int q = (int)rintf(s * 16.0f);
  return q * 16384 + idx;
}

#define GLDS16(gp, lp) \
  __builtin_amdgcn_global_load_lds((const __attribute__((address_space(1))) void*)(gp), \
                                   (__attribute__((address_space(3))) void*)(lp), 16, 0, 0)

// barrier with compiler memory fence only — NO sched_barrier(0) (m141 lesson)
__device__ __forceinline__ void sbar() {
  asm volatile("" ::: "memory");
  __builtin_amdgcn_s_barrier();
  asm volatile("" ::: "memory");
}

// ---------------- kernel 0: c2[c] = sum(codebook[c]^2) ----------------
__global__ __launch_bounds__(256) void c2_kernel(const float* __restrict__ cb,
                                                 float* __restrict__ c2) {
  const int code = blockIdx.x;
  const int t = threadIdx.x, lane = t & 63, wid = t >> 6;
  f32x4 v = *(const f32x4*)(cb + (size_t)code * DIM + t * 4);
  float s = v[0]*v[0] + v[1]*v[1] + v[2]*v[2] + v[3]*v[3];
  #pragma unroll
  for (int off = 32; off; off >>= 1) s += __shfl_down(s, off);
  __shared__ float part[4];
  if (lane == 0) part[wid] = s;
  __syncthreads();
  if (t == 0) c2[code] = part[0] + part[1] + part[2] + part[3];
}

// ---------------- kernel 0b: f32 -> bf16, pre-swizzled 256x64-tile-blocked layout ----------------
__global__ __launch_bounds__(256) void convert_swz256(const float* __restrict__ src,
                                                      ushort* __restrict__ dst) {
  const int chunk = blockIdx.x * 256 + threadIdx.x;   // [0, 64*16*2048)
  const int pc  = chunk & 2047;
  const int kt  = (chunk >> 11) & 15;
  const int m   = chunk >> 15;
  const int row = pc >> 3;
  const int g   = (pc & 7) ^ (row & 7);
  const float* s = src + (size_t)(m * 256 + row) * DIM + kt * 64 + g * 8;
  f32x4 a0 = *(const f32x4*)s;
  f32x4 a1 = *(const f32x4*)(s + 4);
  bf16x8 p;
  #pragma unroll
  for (int j = 0; j < 4; ++j) {
    p[j]     = (short)f2bf(a0[j]);
    p[j + 4] = (short)f2bf(a1[j]);
  }
  *(bf16x8*)(dst + (size_t)chunk * 8) = p;
}

// ---------------- kernel 1: 256^2 8-phase bf16 MFMA GEMM + per-(row,256-block) top-2 ----------------
#define STAGE_HALF(LS, BASE, KT, H) do {                                          \
    _Pragma("unroll")                                                             \
    for (int i_ = 0; i_ < 2; ++i_) {                                              \
      const int cb_ = (H) * 1024 + (i_ * 8 + w) * 64;                             \
      GLDS16((BASE) + (size_t)((KT) * TCH + cb_ + lane) * 8, &(LS)[cb_ * 8]);     \
    } } while (0)

#define RD_A4(DST, LS, MIB) do {                                                  \
    _Pragma("unroll")                                                             \
    for (int mi_ = 0; mi_ < 4; ++mi_) {                                           \
      _Pragma("unroll")                                                           \
      for (int ks_ = 0; ks_ < 2; ++ks_) {                                         \
        const int r_ = wm * 128 + ((MIB) + mi_) * 16 + l15;                       \
        const int g_ = ks_ * 4 + kgrp;                                            \
        DST[mi_][ks_] = *(const bf16x8*)&(LS)[(r_ * 8 + (g_ ^ (r_ & 7))) * 8];    \
      } } } while (0)

#define RD_B2(DST, LS, NIB) do {                                                  \
    _Pragma("unroll")                                                             \
    for (int ni_ = 0; ni_ < 2; ++ni_) {                                           \
      _Pragma("unroll")                                                           \
      for (int ks_ = 0; ks_ < 2; ++ks_) {                                         \
        const int c_ = wn * 64 + ((NIB) + ni_) * 16 + l15;                        \
        const int g_ = ks_ * 4 + kgrp;                                            \
        DST[ni_][ks_] = *(const bf16x8*)&(LS)[(c_ * 8 + (g_ ^ (c_ & 7))) * 8];    \
      } } } while (0)

// ks OUTERMOST: 8 independent MFMAs between dependent accumulator reuses.
#define MMA_Q(MB, NB, AF, BF) do {                                                \
    __builtin_amdgcn_s_setprio(1);                                                \
    _Pragma("unroll")                                                             \
    for (int ks_ = 0; ks_ < 2; ++ks_) {                                           \
      _Pragma("unroll")                                                           \
      for (int mi_ = 0; mi_ < 4; ++mi_) {                                         \
        _Pragma("unroll")                                                         \
        for (int ni_ = 0; ni_ < 2; ++ni_)                                         \
          acc[(MB) + mi_][(NB) + ni_] = __builtin_amdgcn_mfma_f32_16x16x32_bf16(  \
              AF[mi_][ks_], BF[ni_][ks_], acc[(MB) + mi_][(NB) + ni_], 0, 0, 0);  \
      } }                                                                         \
    __builtin_amdgcn_s_setprio(0);                                                \
  } while (0)

__global__ __launch_bounds__(512, 2) void snap_gemm256(const ushort* __restrict__ xs,
                                                       const ushort* __restrict__ cs,
                                                       const float* __restrict__ c2,
                                                       int* __restrict__ cand) {
  __shared__ ushort lsA[3][16384];   // 3-deep A ring (96 KB)
  __shared__ ushort lsB[2][16384];   // 2-deep B (64 KB)

  const int t    = threadIdx.x;
  const int lane = t & 63;
  const int w    = t >> 6;          // 0..7
  const int wm   = w >> 2;          // 0..1
  const int wn   = w & 3;           // 0..3
  const int l15  = lane & 15;
  const int kgrp = lane >> 4;

  // XCD-aware swizzle (bijective: 4096 % 8 == 0)
  const int bid = blockIdx.x;
  const int swz = (bid & 7) * 512 + (bid >> 3);
  const int bm  = swz & 63;
  const int bn  = swz >> 6;

  const ushort* xbase = xs + (size_t)bm * (16 * TCH) * 8;
  const ushort* cbase = cs + (size_t)bn * (16 * TCH) * 8;

  f32x4 acc[8][4];
  #pragma unroll
  for (int mi = 0; mi < 8; ++mi)
    #pragma unroll
    for (int ni = 0; ni < 4; ++ni)
      acc[mi][ni] = (f32x4){0.f, 0.f, 0.f, 0.f};

  bf16x8 aF[4][2], bF0[2][2], bF1[2][2];

  // ---- prologue ----
  STAGE_HALF(lsA[0], xbase, 0, 0);
  STAGE_HALF(lsA[0], xbase, 0, 1);
  STAGE_HALF(lsB[0], cbase, 0, 0);
  STAGE_HALF(lsB[0], cbase, 0, 1);
  STAGE_HALF(lsA[1], xbase, 1, 0);
  STAGE_HALF(lsA[1], xbase, 1, 1);
  STAGE_HALF(lsB[1], cbase, 1, 0);
  STAGE_HALF(lsB[1], cbase, 1, 1);
  asm volatile("s_waitcnt vmcnt(8)" ::: "memory");
  sbar();

  for (int kt = 0; kt < NT; ++kt) {
    const ushort* curA = lsA[kt % 3];
    const ushort* curB = lsB[kt & 1];
    ushort* nxtA = lsA[(kt + 2) % 3];
    ushort* nxtB = lsB[kt & 1];
    const bool st = (kt + 2 < NT);

    // ---- P0: stage A(t+2)-lo; read A(mi0-3) + B(ni0-1) ----
    if (st) STAGE_HALF(nxtA, xbase, kt + 2, 0);
    RD_A4(aF, curA, 0);
    RD_B2(bF0, curB, 0);
    asm volatile("s_waitcnt lgkmcnt(8)" ::: "memory");
    sbar();
    MMA_Q(0, 0, aF, bF0);
    sbar();

    // ---- P1: stage A(t+2)-hi; read B(ni2-3) ----
    if (st) STAGE_HALF(nxtA, xbase, kt + 2, 1);
    RD_B2(bF1, curB, 2);
    sbar();
    MMA_Q(0, 2, aF, bF1);
    sbar();

    // ---- P2: stage B(t+2)-lo; read A(mi4-7) ----
    if (st) STAGE_HALF(nxtB, cbase, kt + 2, 0);
    RD_A4(aF, curA, 4);
    sbar();
    MMA_Q(4, 0, aF, bF0);
    sbar();

    // ---- P3: stage B(t+2)-hi; MFMA; guard ----
    if (st) STAGE_HALF(nxtB, cbase, kt + 2, 1);
    sbar();
    MMA_Q(4, 2, aF, bF1);
    if (st)                { asm volatile("s_waitcnt vmcnt(8)" ::: "memory"); }
    else if (kt == NT - 2) { asm volatile("s_waitcnt vmcnt(0)" ::: "memory"); }
    sbar();
  }

  __syncthreads();   // full drain before overlaying redbuf on lsA

  // ---- epilogue: per-row top-2 over this block's 256 columns (32-bit keys) ----
  int* red = (int*)&lsA[0][0];   // [4][256][2] i32 = 8 KB
  float c2v[4];
  int   colv[4];
  #pragma unroll
  for (int ni = 0; ni < 4; ++ni) {
    colv[ni] = bn * 256 + wn * 64 + ni * 16 + l15;
    c2v[ni]  = c2[colv[ni]];
  }

  #pragma unroll
  for (int mi = 0; mi < 8; ++mi) {
    #pragma unroll
    for (int r = 0; r < 4; ++r) {
      int a = packKey32(fmaf(-2.0f, acc[mi][0][r], c2v[0]), colv[0]);
      int b = packKey32(fmaf(-2.0f, acc[mi][1][r], c2v[1]), colv[1]);
      int c = packKey32(fmaf(-2.0f, acc[mi][2][r], c2v[2]), colv[2]);
      int d = packKey32(fmaf(-2.0f, acc[mi][3][r], c2v[3]), colv[3]);
      int lo1 = imin(a, b), hi1 = imax(a, b);
      int lo2 = imin(c, d), hi2 = imax(c, d);
      int k1 = imin(lo1, lo2);
      int k2 = imin(imax(lo1, lo2), imin(hi1, hi2));
      #pragma unroll
      for (int m = 1; m < 16; m <<= 1) {
        int o1 = __shfl_xor(k1, m);
        int o2 = __shfl_xor(k2, m);
        int n1 = imin(k1, o1);
        int n2 = imin(imax(k1, o1), imin(k2, o2));
        k1 = n1; k2 = n2;
      }
      if (l15 == 0) {
        int rl = wm * 128 + mi * 16 + kgrp * 4 + r;
        red[(wn * 256 + rl) * 2 + 0] = k1;
        red[(wn * 256 + rl) * 2 + 1] = k2;
      }
    }
  }
  __syncthreads();

  if (t < 256) {
    int k1 = red[(0 * 256 + t) * 2 + 0];
    int k2 = red[(0 * 256 + t) * 2 + 1];
    #pragma unroll
    for (int q = 1; q < 4; ++q) {
      int p1 = red[(q * 256 + t) * 2 + 0];
      int p2 = red[(q * 256 + t) * 2 + 1];
      int n1 = imin(k1, p1);
      int n2 = imin(imax(k1, p1), imin(k2, p2));
      k1 = n1; k2 = n2;
    }
    size_t o = (size_t)(bm * 256 + t) * 128 + (size_t)bn * 2;
    cand[o]     = k1;
    cand[o + 1] = k2;
  }
}

// ---------------- kernel 1 (fallback, known-good structure): on-the-fly 128^2 ----------------
__global__ __launch_bounds__(256) void snap_gemm_slow(const float* __restrict__ x,
                                                      const float* __restrict__ cb,
                                                      const float* __restrict__ c2,
                                                      int* __restrict__ cand) {
  __shared__ ushort lsA[2][8192];
  __shared__ ushort lsB[2][8192];
  __shared__ int redbuf[2][128][2];

  const int t    = threadIdx.x;
  const int lane = t & 63;
  const int wid  = t >> 6;
  const int wm   = wid & 1;
  const int wn   = wid >> 1;
  const int l15  = lane & 15;
  const int kgrp = lane >> 4;

  const int bm = blockIdx.x & 127;
  const int bn = blockIdx.x >> 7;
  const int rowBase = bm * 128;
  const int colBase = bn * 128;

  const float* aptr[4];
  const float* bptr[4];
  int ldsOff[4];
  #pragma unroll
  for (int i = 0; i < 4; ++i) {
    int pc = t + 256 * i;
    int row = pc >> 3;
    int g = (pc & 7) ^ (row & 7);
    aptr[i] = x  + (size_t)(rowBase + row) * DIM + g * 8;
    bptr[i] = cb + (size_t)(colBase + row) * DIM + g * 8;
    ldsOff[i] = pc * 8;
  }

  f32x4 acc[4][4];
  #pragma unroll
  for (int mi = 0; mi < 4; ++mi)
    #pragma unroll
    for (int ni = 0; ni < 4; ++ni)
      acc[mi][ni] = (f32x4){0.f, 0.f, 0.f, 0.f};

  auto STAGE = [&](int buf, int kt) {
    const int kOff = kt * 64;
    #pragma unroll
    for (int i = 0; i < 4; ++i) {
      f32x4 a0 = *(const f32x4*)(aptr[i] + kOff);
      f32x4 a1 = *(const f32x4*)(aptr[i] + kOff + 4);
      f32x4 b0 = *(const f32x4*)(bptr[i] + kOff);
      f32x4 b1 = *(const f32x4*)(bptr[i] + kOff + 4);
      bf16x8 pa, pb;
      #pragma unroll
      for (int j = 0; j < 4; ++j) {
        pa[j]     = (short)f2bf(a0[j]);
        pa[j + 4] = (short)f2bf(a1[j]);
        pb[j]     = (short)f2bf(b0[j]);
        pb[j + 4] = (short)f2bf(b1[j]);
      }
      *(bf16x8*)(&lsA[buf][ldsOff[i]]) = pa;
      *(bf16x8*)(&lsB[buf][ldsOff[i]]) = pb;
    }
  };

  STAGE(0, 0);
  __syncthreads();

  for (int kt = 0; kt < DIM / 64; ++kt) {
    const int cur = kt & 1;
    if (kt < DIM / 64 - 1) STAGE(cur ^ 1, kt + 1);

    const ushort* bA = &lsA[cur][0];
    const ushort* bB = &lsB[cur][0];
    #pragma unroll
    for (int ks = 0; ks < 2; ++ks) {
      const int gidx = ks * 4 + kgrp;
      bf16x8 af[4], bfr[4];
      #pragma unroll
      for (int mi = 0; mi < 4; ++mi) {
        int r_ = wm * 64 + mi * 16 + l15;
        af[mi] = *(const bf16x8*)(bA + (r_ * 8 + (gidx ^ (r_ & 7))) * 8);
      }
      #pragma unroll
      for (int ni = 0; ni < 4; ++ni) {
        int c_ = wn * 64 + ni * 16 + l15;
        bfr[ni] = *(const bf16x8*)(bB + (c_ * 8 + (gidx ^ (c_ & 7))) * 8);
      }
      #pragma unroll
      for (int mi = 0; mi < 4; ++mi)
        #pragma unroll
        for (int ni = 0; ni < 4; ++ni)
          acc[mi][ni] = __builtin_amdgcn_mfma_f32_16x16x32_bf16(af[mi], bfr[ni], acc[mi][ni], 0, 0, 0);
    }
    __syncthreads();
  }

  float c2v[4];
  int   colv[4];
  #pragma unroll
  for (int ni = 0; ni < 4; ++ni) {
    colv[ni] = colBase + wn * 64 + ni * 16 + l15;
    c2v[ni]  = c2[colv[ni]];
  }

  #pragma unroll
  for (int mi = 0; mi < 4; ++mi) {
    #pragma unroll
    for (int r = 0; r < 4; ++r) {
      int a = packKey32(fmaf(-2.0f, acc[mi][0][r], c2v[0]), colv[0]);
      int b = packKey32(fmaf(-2.0f, acc[mi][1][r], c2v[1]), colv[1]);
      int c = packKey32(fmaf(-2.0f, acc[mi][2][r], c2v[2]), colv[2]);
      int d = packKey32(fmaf(-2.0f, acc[mi][3][r], c2v[3]), colv[3]);
      int lo1 = imin(a, b), hi1 = imax(a, b);
      int lo2 = imin(c, d), hi2 = imax(c, d);
      int k1 = imin(lo1, lo2);
      int k2 = imin(imax(lo1, lo2), imin(hi1, hi2));
      #pragma unroll
      for (int m = 1; m < 16; m <<= 1) {
        int o1 = __shfl_xor(k1, m);
        int o2 = __shfl_xor(k2, m);
        int n1 = imin(k1, o1);
        int n2 = imin(imax(k1, o1), imin(k2, o2));
        k1 = n1; k2 = n2;
      }
      if (l15 == 0) {
        int rl = wm * 64 + mi * 16 + kgrp * 4 + r;
        redbuf[wn][rl][0] = k1;
        redbuf[wn][rl][1] = k2;
      }
    }
  }
  __syncthreads();

  if (t < 128) {
    int a1 = redbuf[0][t][0], a2 = redbuf[0][t][1];
    int b1 = redbuf[1][t][0], b2 = redbuf[1][t][1];
    int m1 = imin(a1, b1);
    int m2 = imin(imax(a1, b1), imin(a2, b2));
    size_t o = (size_t)(rowBase + t) * 256 + (size_t)bn * 2;
    cand[o]     = m1;
    cand[o + 1] = m2;
  }
}

// ---------------- kernel 2: exact f64 rerank of candidates within margin of pool-min ----------------
__global__ __launch_bounds__(256) void rerank(const float* __restrict__ x,
                                              const float* __restrict__ cb,
                                              const int* __restrict__ cand,
                                              int* __restrict__ bestidx,
                                              int poolN) {
  const int row = blockIdx.x;
  const int t = threadIdx.x, lane = t & 63, wid = t >> 6;
  __shared__ int    smin[4];
  __shared__ int    gshared;
  __shared__ double dpart[4];
  __shared__ int    cnt;
  __shared__ int    list[64];

  int my = (t < poolN) ? cand[(size_t)row * poolN + t] : 0x7FFFFFFF;
  int k = my;
  #pragma unroll
  for (int off = 32; off; off >>= 1) k = imin(k, __shfl_down(k, off));
  if (lane == 0) smin[wid] = k;
  if (t == 0) cnt = 0;
  __syncthreads();
  if (t == 0) {
    int g = smin[0];
    for (int i = 1; i < 4; ++i) g = imin(g, smin[i]);
    gshared = g;
  }
  __syncthreads();

  const int gq = gshared >> 14;        // arithmetic shift: floor of quantized score
  if ((my >> 14) <= gq + MARGIN_Q) {
    int p = atomicAdd(&cnt, 1);
    if (p < 64) list[p] = my & 16383;
  }
  __syncthreads();
  int n = cnt; if (n > 64) n = 64;

  uint64_t best = ~0ull;
  const float* xr = x + (size_t)row * DIM;
  for (int i = 0; i < n; ++i) {
    const int cidx = list[i];
    const float* cr = cb + (size_t)cidx * DIM;
    double p = 0.0;
    #pragma unroll
    for (int j = 0; j < 4; ++j) {
      int d = t + 256 * j;
      double diff = (double)xr[d] - (double)cr[d];
      p += diff * diff;
    }
    #pragma unroll
    for (int off = 32; off; off >>= 1) p += __shfl_down(p, off);
    if (lane == 0) dpart[wid] = p;
    __syncthreads();
    if (t == 0) {
      double d2 = dpart[0] + dpart[1] + dpart[2] + dpart[3];
      uint64_t bits = (uint64_t)__double_as_longlong(d2);   // d2 >= 0: order-preserving
      uint64_t key = (bits & ~0x3FFFull) | (uint32_t)cidx;  // tie -> lowest idx
      if (key < best) best = key;
    }
    __syncthreads();
  }
  if (t == 0) bestidx[row] = (int)(best & 0x3FFFull);
}

// ---------------- kernel 3: gather winning codebook rows ----------------
__global__ __launch_bounds__(256) void gather_rows(const float* __restrict__ cb,
                                                   const int* __restrict__ bestidx,
                                                   float* __restrict__ out) {
  const int row = blockIdx.x;
  const int idx = bestidx[row];
  f32x4 v = *(const f32x4*)(cb + (size_t)idx * DIM + threadIdx.x * 4);
  *(f32x4*)(out + (size_t)row * DIM + threadIdx.x * 4) = v;
}

extern "C" void kernel_launch(void* const* d_in, const int* in_sizes, int n_in,
                              void* d_out, int out_size, void* d_ws, size_t ws_size,
                              hipStream_t stream) {
  const float* x  = (const float*)d_in[0];
  const float* cb = (const float*)d_in[1];
  float* out = (float*)d_out;

  float* c2      = (float*)d_ws;                        // 64 KB
  int*   bestidx = (int*)((char*)d_ws + 64 * 1024);     // 64 KB

  const size_t candBytes = (size_t)NROWS * 128 * 4;     // 8 MB (32-bit keys)
  const size_t needFast  = 128 * 1024 + candBytes;

  c2_kernel<<<NCODES, 256, 0, stream>>>(cb, c2);

  if (ws_size >= needFast) {
    ushort* xs = (ushort*)d_out;                        // 33.5 MB (bf16, tile-blocked+swizzled)
    ushort* cs = xs + (size_t)NROWS * DIM;              // 33.5 MB
    int* cand = (int*)((char*)d_ws + 128 * 1024);

    convert_swz256<<<8192, 256, 0, stream>>>(x,  xs);
    convert_swz256<<<8192, 256, 0, stream>>>(cb, cs);
    snap_gemm256<<<4096, 512, 0, stream>>>(xs, cs, c2, cand);
    rerank<<<NROWS, 256, 0, stream>>>(x, cb, cand, bestidx, 128);
    gather_rows<<<NROWS, 256, 0, stream>>>(cb, bestidx, out);
  } else {
    int* cand = (int*)d_out;                            // 16 MB, overwritten by gather later
    snap_gemm_slow<<<(NROWS / 128) * (NCODES / 128), 256, 0, stream>>>(x, cb, c2, cand);
    rerank<<<NROWS, 256, 0, stream>>>(x, cb, cand, bestidx, 256);
    gather_rows<<<NROWS, 256, 0, stream>>>(cb, bestidx, out);
  }
}

// Round 6
// 677.897 us; speedup vs baseline: 1.2110x; 1.2110x over previous
//
#include <hip/hip_runtime.h>
#include <hip/hip_bf16.h>
#include <stdint.h>

// x: (4,4096,1024) f32 -> 16384 x 1024 rows; codebook: (16384,1024) f32
#define NROWS  16384
#define NCODES 16384
#define DIM    1024
#define NT     16          // DIM / BK,  BK = 64
#define TCH    2048        // 16B chunks per 256x64 tile
#define MARGIN_Q 52        // quantized margin: 3.0 (bf16 ~20 sigma) + quant slop, in 1/16 units

typedef float f32x4  __attribute__((ext_vector_type(4)));
typedef short bf16x8 __attribute__((ext_vector_type(8)));

__device__ __forceinline__ ushort f2bf(float f) {
  uint32_t u = __float_as_uint(f);
  uint32_t r = u + 0x7FFFu + ((u >> 16) & 1u);
  return (ushort)(r >> 16);
}
__device__ __forceinline__ int imin(int a, int b){ return a < b ? a : b; }
__device__ __forceinline__ int imax(int a, int b){ return a < b ? b : a; }
__device__ __forceinline__ int packKey32(float s, int idx) {
  int q = (int)rintf(s * 16.0f);
  return q * 16384 + idx;
}

#define GLDS16(gp, lp) \
  __builtin_amdgcn_global_load_lds((const __attribute__((address_space(1))) void*)(gp), \
                                   (__attribute__((address_space(3))) void*)(lp), 16, 0, 0)

__device__ __forceinline__ void sbar() {
  asm volatile("" ::: "memory");
  __builtin_amdgcn_s_barrier();
  asm volatile("" ::: "memory");
}

// ---------------- kernel 0: c2[c] = sum(codebook[c]^2) ----------------
__global__ __launch_bounds__(256) void c2_kernel(const float* __restrict__ cb,
                                                 float* __restrict__ c2) {
  const int code = blockIdx.x;
  const int t = threadIdx.x, lane = t & 63, wid = t >> 6;
  f32x4 v = *(const f32x4*)(cb + (size_t)code * DIM + t * 4);
  float s = v[0]*v[0] + v[1]*v[1] + v[2]*v[2] + v[3]*v[3];
  #pragma unroll
  for (int off = 32; off; off >>= 1) s += __shfl_down(s, off);
  __shared__ float part[4];
  if (lane == 0) part[wid] = s;
  __syncthreads();
  if (t == 0) c2[code] = part[0] + part[1] + part[2] + part[3];
}

// ---------------- kernel 0b: f32 -> bf16, pre-swizzled 256x64-tile-blocked layout ----------------
__global__ __launch_bounds__(256) void convert_swz256(const float* __restrict__ src,
                                                      ushort* __restrict__ dst) {
  const int chunk = blockIdx.x * 256 + threadIdx.x;   // [0, 64*16*2048)
  const int pc  = chunk & 2047;
  const int kt  = (chunk >> 11) & 15;
  const int m   = chunk >> 15;
  const int row = pc >> 3;
  const int g   = (pc & 7) ^ (row & 7);
  const float* s = src + (size_t)(m * 256 + row) * DIM + kt * 64 + g * 8;
  f32x4 a0 = *(const f32x4*)s;
  f32x4 a1 = *(const f32x4*)(s + 4);
  bf16x8 p;
  #pragma unroll
  for (int j = 0; j < 4; ++j) {
    p[j]     = (short)f2bf(a0[j]);
    p[j + 4] = (short)f2bf(a1[j]);
  }
  *(bf16x8*)(dst + (size_t)chunk * 8) = p;
}

// ---------------- kernel 1: 256^2 8-phase bf16 MFMA GEMM + per-(row,256-block) top-2 ----------------
// All LDS read addrs collapse to 6 base pointers because (row&7)==(l15&7) for
// every fragment row: addr = base[buf][ks] + {mi,ni}*1024 (compile-time imm).

#define STAGE_A(BUF, KT, H) do {                                                  \
    GLDS16(ga + ((KT)*16384 + (H)*8192),        &lsA[BUF][(H)*8192 + w*512]);     \
    GLDS16(ga + ((KT)*16384 + (H)*8192 + 4096), &lsA[BUF][(H)*8192 + w*512 + 4096]); \
  } while (0)
#define STAGE_B(BUF, KT, H) do {                                                  \
    GLDS16(gb + ((KT)*16384 + (H)*8192),        &lsB[BUF][(H)*8192 + w*512]);     \
    GLDS16(gb + ((KT)*16384 + (H)*8192 + 4096), &lsB[BUF][(H)*8192 + w*512 + 4096]); \
  } while (0)

#define RD_A(MIB, BUF) do {                                                       \
    _Pragma("unroll")                                                             \
    for (int mi_ = 0; mi_ < 4; ++mi_) {                                           \
      aF[mi_][0] = *(const bf16x8*)(A0[BUF] + ((MIB) + mi_) * 1024);              \
      aF[mi_][1] = *(const bf16x8*)(A1[BUF] + ((MIB) + mi_) * 1024);              \
    } } while (0)
#define RD_Bx(DST, NIB, BUF) do {                                                 \
    _Pragma("unroll")                                                             \
    for (int ni_ = 0; ni_ < 2; ++ni_) {                                           \
      DST[ni_][0] = *(const bf16x8*)(B0[BUF] + ((NIB) + ni_) * 1024);             \
      DST[ni_][1] = *(const bf16x8*)(B1[BUF] + ((NIB) + ni_) * 1024);             \
    } } while (0)

#define MMA_Q(MB, NB, AF, BF) do {                                                \
    __builtin_amdgcn_s_setprio(1);                                                \
    _Pragma("unroll")                                                             \
    for (int ks_ = 0; ks_ < 2; ++ks_) {                                           \
      _Pragma("unroll")                                                           \
      for (int mi_ = 0; mi_ < 4; ++mi_) {                                         \
        _Pragma("unroll")                                                         \
        for (int ni_ = 0; ni_ < 2; ++ni_)                                         \
          acc[(MB) + mi_][(NB) + ni_] = __builtin_amdgcn_mfma_f32_16x16x32_bf16(  \
              AF[mi_][ks_], BF[ni_][ks_], acc[(MB) + mi_][(NB) + ni_], 0, 0, 0);  \
      } }                                                                         \
    __builtin_amdgcn_s_setprio(0);                                                \
  } while (0)

#define G8  asm volatile("s_waitcnt vmcnt(8)" ::: "memory")
#define G0  asm volatile("s_waitcnt vmcnt(0)" ::: "memory")
#define NOG do {} while (0)

// One K-tile = 4 phases. AC/BC: current buf idx; AN/BN_: stage-target bufs.
#define TILE(KT, AC, BC, AN, BN_, DOST, GUARD) do {                               \
    if (DOST) STAGE_A(AN, (KT) + 2, 0);                                           \
    RD_A(0, AC);                                                                  \
    RD_Bx(bF0, 0, BC);                                                            \
    sbar(); MMA_Q(0, 0, aF, bF0); sbar();                                         \
    if (DOST) STAGE_A(AN, (KT) + 2, 1);                                           \
    RD_Bx(bF1, 2, BC);                                                            \
    sbar(); MMA_Q(0, 2, aF, bF1); sbar();                                         \
    if (DOST) STAGE_B(BN_, (KT) + 2, 0);                                          \
    RD_A(4, AC);                                                                  \
    sbar(); MMA_Q(4, 0, aF, bF0); sbar();                                         \
    if (DOST) STAGE_B(BN_, (KT) + 2, 1);                                          \
    sbar(); MMA_Q(4, 2, aF, bF1);                                                 \
    GUARD;                                                                        \
    sbar();                                                                       \
  } while (0)

__global__ __launch_bounds__(512, 2) void snap_gemm256(const ushort* __restrict__ xs,
                                                       const ushort* __restrict__ cs,
                                                       const float* __restrict__ c2,
                                                       int* __restrict__ cand) {
  __shared__ ushort lsA[3][16384];   // 3-deep A ring (96 KB)
  __shared__ ushort lsB[2][16384];   // 2-deep B (64 KB)

  const int t    = threadIdx.x;
  const int lane = t & 63;
  const int w    = t >> 6;          // 0..7
  const int wm   = w >> 2;          // 0..1
  const int wn   = w & 3;           // 0..3
  const int l15  = lane & 15;
  const int kgrp = lane >> 4;

  // XCD-aware swizzle (bijective: 4096 % 8 == 0)
  const int bid = blockIdx.x;
  const int swz = (bid & 7) * 512 + (bid >> 3);
  const int bm  = swz & 63;
  const int bn  = swz >> 6;

  const ushort* xbase = xs + (size_t)bm * (16 * TCH) * 8;
  const ushort* cbase = cs + (size_t)bn * (16 * TCH) * 8;
  const ushort* ga = xbase + w * 512 + lane * 8;   // per-thread stage src base
  const ushort* gb = cbase + w * 512 + lane * 8;

  // Precomputed LDS read base pointers (ushort units).
  const int sw0  = ( kgrp      ^ (l15 & 7)) * 8;
  const int sw1  = ((4 | kgrp) ^ (l15 & 7)) * 8;
  const int arow = (wm * 128 + l15) * 64;
  const int brow = (wn * 64  + l15) * 64;
  const ushort* A0[3]; const ushort* A1[3];
  const ushort* B0[2]; const ushort* B1[2];
  #pragma unroll
  for (int b = 0; b < 3; ++b) { A0[b] = &lsA[b][arow + sw0]; A1[b] = &lsA[b][arow + sw1]; }
  #pragma unroll
  for (int b = 0; b < 2; ++b) { B0[b] = &lsB[b][brow + sw0]; B1[b] = &lsB[b][brow + sw1]; }

  f32x4 acc[8][4];
  #pragma unroll
  for (int mi = 0; mi < 8; ++mi)
    #pragma unroll
    for (int ni = 0; ni < 4; ++ni)
      acc[mi][ni] = (f32x4){0.f, 0.f, 0.f, 0.f};

  bf16x8 aF[4][2], bF0[2][2], bF1[2][2];

  // ---- prologue: tiles 0 and 1 ----
  STAGE_A(0, 0, 0); STAGE_A(0, 0, 1);
  STAGE_B(0, 0, 0); STAGE_B(0, 0, 1);
  STAGE_A(1, 1, 0); STAGE_A(1, 1, 1);
  STAGE_B(1, 1, 0); STAGE_B(1, 1, 1);
  G8;                  // tile 0 landed; tile 1 may fly
  sbar();

  // Fully unrolled K-loop: bufA = kt%3, bufB = kt&1, nxtA = (kt+2)%3, nxtB = kt&1.
  TILE(0 , 0, 0, 2, 0, 1, G8);
  TILE(1 , 1, 1, 0, 1, 1, G8);
  TILE(2 , 2, 0, 1, 0, 1, G8);
  TILE(3 , 0, 1, 2, 1, 1, G8);
  TILE(4 , 1, 0, 0, 0, 1, G8);
  TILE(5 , 2, 1, 1, 1, 1, G8);
  TILE(6 , 0, 0, 2, 0, 1, G8);
  TILE(7 , 1, 1, 0, 1, 1, G8);
  TILE(8 , 2, 0, 1, 0, 1, G8);
  TILE(9 , 0, 1, 2, 1, 1, G8);
  TILE(10, 1, 0, 0, 0, 1, G8);
  TILE(11, 2, 1, 1, 1, 1, G8);
  TILE(12, 0, 0, 2, 0, 1, G8);
  TILE(13, 1, 1, 0, 1, 1, G8);
  TILE(14, 2, 0, 1, 0, 0, G0);
  TILE(15, 0, 1, 2, 1, 0, NOG);

  __syncthreads();   // full drain before overlaying redbuf on lsA

  // ---- epilogue: per-row top-2 over this block's 256 columns (32-bit keys) ----
  int* red = (int*)&lsA[0][0];   // [4][256][2] i32 = 8 KB
  float c2v[4];
  int   colv[4];
  #pragma unroll
  for (int ni = 0; ni < 4; ++ni) {
    colv[ni] = bn * 256 + wn * 64 + ni * 16 + l15;
    c2v[ni]  = c2[colv[ni]];
  }

  #pragma unroll
  for (int mi = 0; mi < 8; ++mi) {
    #pragma unroll
    for (int r = 0; r < 4; ++r) {
      int a = packKey32(fmaf(-2.0f, acc[mi][0][r], c2v[0]), colv[0]);
      int b = packKey32(fmaf(-2.0f, acc[mi][1][r], c2v[1]), colv[1]);
      int c = packKey32(fmaf(-2.0f, acc[mi][2][r], c2v[2]), colv[2]);
      int d = packKey32(fmaf(-2.0f, acc[mi][3][r], c2v[3]), colv[3]);
      int lo1 = imin(a, b), hi1 = imax(a, b);
      int lo2 = imin(c, d), hi2 = imax(c, d);
      int k1 = imin(lo1, lo2);
      int k2 = imin(imax(lo1, lo2), imin(hi1, hi2));
      #pragma unroll
      for (int m = 1; m < 16; m <<= 1) {
        int o1 = __shfl_xor(k1, m);
        int o2 = __shfl_xor(k2, m);
        int n1 = imin(k1, o1);
        int n2 = imin(imax(k1, o1), imin(k2, o2));
        k1 = n1; k2 = n2;
      }
      if (l15 == 0) {
        int rl = wm * 128 + mi * 16 + kgrp * 4 + r;
        red[(wn * 256 + rl) * 2 + 0] = k1;
        red[(wn * 256 + rl) * 2 + 1] = k2;
      }
    }
  }
  __syncthreads();

  if (t < 256) {
    int k1 = red[(0 * 256 + t) * 2 + 0];
    int k2 = red[(0 * 256 + t) * 2 + 1];
    #pragma unroll
    for (int q = 1; q < 4; ++q) {
      int p1 = red[(q * 256 + t) * 2 + 0];
      int p2 = red[(q * 256 + t) * 2 + 1];
      int n1 = imin(k1, p1);
      int n2 = imin(imax(k1, p1), imin(k2, p2));
      k1 = n1; k2 = n2;
    }
    size_t o = (size_t)(bm * 256 + t) * 128 + (size_t)bn * 2;
    cand[o]     = k1;
    cand[o + 1] = k2;
  }
}

// ---------------- kernel 1 (fallback, known-good structure): on-the-fly 128^2 ----------------
__global__ __launch_bounds__(256) void snap_gemm_slow(const float* __restrict__ x,
                                                      const float* __restrict__ cb,
                                                      const float* __restrict__ c2,
                                                      int* __restrict__ cand) {
  __shared__ ushort lsA[2][8192];
  __shared__ ushort lsB[2][8192];
  __shared__ int redbuf[2][128][2];

  const int t    = threadIdx.x;
  const int lane = t & 63;
  const int wid  = t >> 6;
  const int wm   = wid & 1;
  const int wn   = wid >> 1;
  const int l15  = lane & 15;
  const int kgrp = lane >> 4;

  const int bm = blockIdx.x & 127;
  const int bn = blockIdx.x >> 7;
  const int rowBase = bm * 128;
  const int colBase = bn * 128;

  const float* aptr[4];
  const float* bptr[4];
  int ldsOff[4];
  #pragma unroll
  for (int i = 0; i < 4; ++i) {
    int pc = t + 256 * i;
    int row = pc >> 3;
    int g = (pc & 7) ^ (row & 7);
    aptr[i] = x  + (size_t)(rowBase + row) * DIM + g * 8;
    bptr[i] = cb + (size_t)(colBase + row) * DIM + g * 8;
    ldsOff[i] = pc * 8;
  }

  f32x4 acc[4][4];
  #pragma unroll
  for (int mi = 0; mi < 4; ++mi)
    #pragma unroll
    for (int ni = 0; ni < 4; ++ni)
      acc[mi][ni] = (f32x4){0.f, 0.f, 0.f, 0.f};

  auto STAGE = [&](int buf, int kt) {
    const int kOff = kt * 64;
    #pragma unroll
    for (int i = 0; i < 4; ++i) {
      f32x4 a0 = *(const f32x4*)(aptr[i] + kOff);
      f32x4 a1 = *(const f32x4*)(aptr[i] + kOff + 4);
      f32x4 b0 = *(const f32x4*)(bptr[i] + kOff);
      f32x4 b1 = *(const f32x4*)(bptr[i] + kOff + 4);
      bf16x8 pa, pb;
      #pragma unroll
      for (int j = 0; j < 4; ++j) {
        pa[j]     = (short)f2bf(a0[j]);
        pa[j + 4] = (short)f2bf(a1[j]);
        pb[j]     = (short)f2bf(b0[j]);
        pb[j + 4] = (short)f2bf(b1[j]);
      }
      *(bf16x8*)(&lsA[buf][ldsOff[i]]) = pa;
      *(bf16x8*)(&lsB[buf][ldsOff[i]]) = pb;
    }
  };

  STAGE(0, 0);
  __syncthreads();

  for (int kt = 0; kt < DIM / 64; ++kt) {
    const int cur = kt & 1;
    if (kt < DIM / 64 - 1) STAGE(cur ^ 1, kt + 1);

    const ushort* bA = &lsA[cur][0];
    const ushort* bB = &lsB[cur][0];
    #pragma unroll
    for (int ks = 0; ks < 2; ++ks) {
      const int gidx = ks * 4 + kgrp;
      bf16x8 af[4], bfr[4];
      #pragma unroll
      for (int mi = 0; mi < 4; ++mi) {
        int r_ = wm * 64 + mi * 16 + l15;
        af[mi] = *(const bf16x8*)(bA + (r_ * 8 + (gidx ^ (r_ & 7))) * 8);
      }
      #pragma unroll
      for (int ni = 0; ni < 4; ++ni) {
        int c_ = wn * 64 + ni * 16 + l15;
        bfr[ni] = *(const bf16x8*)(bB + (c_ * 8 + (gidx ^ (c_ & 7))) * 8);
      }
      #pragma unroll
      for (int mi = 0; mi < 4; ++mi)
        #pragma unroll
        for (int ni = 0; ni < 4; ++ni)
          acc[mi][ni] = __builtin_amdgcn_mfma_f32_16x16x32_bf16(af[mi], bfr[ni], acc[mi][ni], 0, 0, 0);
    }
    __syncthreads();
  }

  float c2v[4];
  int   colv[4];
  #pragma unroll
  for (int ni = 0; ni < 4; ++ni) {
    colv[ni] = colBase + wn * 64 + ni * 16 + l15;
    c2v[ni]  = c2[colv[ni]];
  }

  #pragma unroll
  for (int mi = 0; mi < 4; ++mi) {
    #pragma unroll
    for (int r = 0; r < 4; ++r) {
      int a = packKey32(fmaf(-2.0f, acc[mi][0][r], c2v[0]), colv[0]);
      int b = packKey32(fmaf(-2.0f, acc[mi][1][r], c2v[1]), colv[1]);
      int c = packKey32(fmaf(-2.0f, acc[mi][2][r], c2v[2]), colv[2]);
      int d = packKey32(fmaf(-2.0f, acc[mi][3][r], c2v[3]), colv[3]);
      int lo1 = imin(a, b), hi1 = imax(a, b);
      int lo2 = imin(c, d), hi2 = imax(c, d);
      int k1 = imin(lo1, lo2);
      int k2 = imin(imax(lo1, lo2), imin(hi1, hi2));
      #pragma unroll
      for (int m = 1; m < 16; m <<= 1) {
        int o1 = __shfl_xor(k1, m);
        int o2 = __shfl_xor(k2, m);
        int n1 = imin(k1, o1);
        int n2 = imin(imax(k1, o1), imin(k2, o2));
        k1 = n1; k2 = n2;
      }
      if (l15 == 0) {
        int rl = wm * 64 + mi * 16 + kgrp * 4 + r;
        redbuf[wn][rl][0] = k1;
        redbuf[wn][rl][1] = k2;
      }
    }
  }
  __syncthreads();

  if (t < 128) {
    int a1 = redbuf[0][t][0], a2 = redbuf[0][t][1];
    int b1 = redbuf[1][t][0], b2 = redbuf[1][t][1];
    int m1 = imin(a1, b1);
    int m2 = imin(imax(a1, b1), imin(a2, b2));
    size_t o = (size_t)(rowBase + t) * 256 + (size_t)bn * 2;
    cand[o]     = m1;
    cand[o + 1] = m2;
  }
}

// ---------------- kernel 2: exact f64 rerank of candidates within margin of pool-min ----------------
__global__ __launch_bounds__(256) void rerank(const float* __restrict__ x,
                                              const float* __restrict__ cb,
                                              const int* __restrict__ cand,
                                              int* __restrict__ bestidx,
                                              int poolN) {
  const int row = blockIdx.x;
  const int t = threadIdx.x, lane = t & 63, wid = t >> 6;
  __shared__ int    smin[4];
  __shared__ int    gshared;
  __shared__ double dpart[4];
  __shared__ int    cnt;
  __shared__ int    list[64];

  int my = (t < poolN) ? cand[(size_t)row * poolN + t] : 0x7FFFFFFF;
  int k = my;
  #pragma unroll
  for (int off = 32; off; off >>= 1) k = imin(k, __shfl_down(k, off));
  if (lane == 0) smin[wid] = k;
  if (t == 0) cnt = 0;
  __syncthreads();
  if (t == 0) {
    int g = smin[0];
    for (int i = 1; i < 4; ++i) g = imin(g, smin[i]);
    gshared = g;
  }
  __syncthreads();

  const int gq = gshared >> 14;
  if ((my >> 14) <= gq + MARGIN_Q) {
    int p = atomicAdd(&cnt, 1);
    if (p < 64) list[p] = my & 16383;
  }
  __syncthreads();
  int n = cnt; if (n > 64) n = 64;

  uint64_t best = ~0ull;
  const float* xr = x + (size_t)row * DIM;
  for (int i = 0; i < n; ++i) {
    const int cidx = list[i];
    const float* cr = cb + (size_t)cidx * DIM;
    double p = 0.0;
    #pragma unroll
    for (int j = 0; j < 4; ++j) {
      int d = t + 256 * j;
      double diff = (double)xr[d] - (double)cr[d];
      p += diff * diff;
    }
    #pragma unroll
    for (int off = 32; off; off >>= 1) p += __shfl_down(p, off);
    if (lane == 0) dpart[wid] = p;
    __syncthreads();
    if (t == 0) {
      double d2 = dpart[0] + dpart[1] + dpart[2] + dpart[3];
      uint64_t bits = (uint64_t)__double_as_longlong(d2);
      uint64_t key = (bits & ~0x3FFFull) | (uint32_t)cidx;
      if (key < best) best = key;
    }
    __syncthreads();
  }
  if (t == 0) bestidx[row] = (int)(best & 0x3FFFull);
}

// ---------------- kernel 3: gather winning codebook rows ----------------
__global__ __launch_bounds__(256) void gather_rows(const float* __restrict__ cb,
                                                   const int* __restrict__ bestidx,
                                                   float* __restrict__ out) {
  const int row = blockIdx.x;
  const int idx = bestidx[row];
  f32x4 v = *(const f32x4*)(cb + (size_t)idx * DIM + threadIdx.x * 4);
  *(f32x4*)(out + (size_t)row * DIM + threadIdx.x * 4) = v;
}

extern "C" void kernel_launch(void* const* d_in, const int* in_sizes, int n_in,
                              void* d_out, int out_size, void* d_ws, size_t ws_size,
                              hipStream_t stream) {
  const float* x  = (const float*)d_in[0];
  const float* cb = (const float*)d_in[1];
  float* out = (float*)d_out;

  float* c2      = (float*)d_ws;                        // 64 KB
  int*   bestidx = (int*)((char*)d_ws + 64 * 1024);     // 64 KB

  const size_t candBytes = (size_t)NROWS * 128 * 4;     // 8 MB (32-bit keys)
  const size_t needFast  = 128 * 1024 + candBytes;

  c2_kernel<<<NCODES, 256, 0, stream>>>(cb, c2);

  if (ws_size >= needFast) {
    ushort* xs = (ushort*)d_out;                        // 33.5 MB (bf16, tile-blocked+swizzled)
    ushort* cs = xs + (size_t)NROWS * DIM;              // 33.5 MB
    int* cand = (int*)((char*)d_ws + 128 * 1024);

    convert_swz256<<<8192, 256, 0, stream>>>(x,  xs);
    convert_swz256<<<8192, 256, 0, stream>>>(cb, cs);
    snap_gemm256<<<4096, 512, 0, stream>>>(xs, cs, c2, cand);
    rerank<<<NROWS, 256, 0, stream>>>(x, cb, cand, bestidx, 128);
    gather_rows<<<NROWS, 256, 0, stream>>>(cb, bestidx, out);
  } else {
    int* cand = (int*)d_out;
    snap_gemm_slow<<<(NROWS / 128) * (NCODES / 128), 256, 0, stream>>>(x, cb, c2, cand);
    rerank<<<NROWS, 256, 0, stream>>>(x, cb, cand, bestidx, 256);
    gather_rows<<<NROWS, 256, 0, stream>>>(cb, bestidx, out);
  }
}

// Round 7
// 661.294 us; speedup vs baseline: 1.2414x; 1.0251x over previous
//
#include <hip/hip_runtime.h>
#include <hip/hip_bf16.h>
#include <stdint.h>

// x: (4,4096,1024) f32 -> 16384 x 1024 rows; codebook: (16384,1024) f32
#define NROWS  16384
#define NCODES 16384
#define DIM    1024
#define NT     16          // DIM / BK,  BK = 64
#define TCH    2048        // 16B chunks per 256x64 tile
#define MARGIN_Q 52        // quantized margin: 3.0 (bf16 ~20 sigma) + quant slop, in 1/16 units

typedef float f32x4  __attribute__((ext_vector_type(4)));
typedef short bf16x8 __attribute__((ext_vector_type(8)));

__device__ __forceinline__ ushort f2bf(float f) {
  uint32_t u = __float_as_uint(f);
  uint32_t r = u + 0x7FFFu + ((u >> 16) & 1u);
  return (ushort)(r >> 16);
}
__device__ __forceinline__ int imin(int a, int b){ return a < b ? a : b; }
__device__ __forceinline__ int imax(int a, int b){ return a < b ? b : a; }
__device__ __forceinline__ int packKey32(float s, int idx) {
  int q = (int)rintf(s * 16.0f);
  return q * 16384 + idx;
}

#define GLDS16(gp, lp) \
  __builtin_amdgcn_global_load_lds((const __attribute__((address_space(1))) void*)(gp), \
                                   (__attribute__((address_space(3))) void*)(lp), 16, 0, 0)

__device__ __forceinline__ void sbar() {
  asm volatile("" ::: "memory");
  __builtin_amdgcn_s_barrier();
  asm volatile("" ::: "memory");
}

// ---------------- kernel 0: c2[c] = sum(codebook[c]^2) ----------------
__global__ __launch_bounds__(256) void c2_kernel(const float* __restrict__ cb,
                                                 float* __restrict__ c2) {
  const int code = blockIdx.x;
  const int t = threadIdx.x, lane = t & 63, wid = t >> 6;
  f32x4 v = *(const f32x4*)(cb + (size_t)code * DIM + t * 4);
  float s = v[0]*v[0] + v[1]*v[1] + v[2]*v[2] + v[3]*v[3];
  #pragma unroll
  for (int off = 32; off; off >>= 1) s += __shfl_down(s, off);
  __shared__ float part[4];
  if (lane == 0) part[wid] = s;
  __syncthreads();
  if (t == 0) c2[code] = part[0] + part[1] + part[2] + part[3];
}

// ---------------- kernel 0b: f32 -> bf16, pre-swizzled 256x64-tile-blocked layout ----------------
__global__ __launch_bounds__(256) void convert_swz256(const float* __restrict__ src,
                                                      ushort* __restrict__ dst) {
  const int chunk = blockIdx.x * 256 + threadIdx.x;   // [0, 64*16*2048)
  const int pc  = chunk & 2047;
  const int kt  = (chunk >> 11) & 15;
  const int m   = chunk >> 15;
  const int row = pc >> 3;
  const int g   = (pc & 7) ^ (row & 7);
  const float* s = src + (size_t)(m * 256 + row) * DIM + kt * 64 + g * 8;
  f32x4 a0 = *(const f32x4*)s;
  f32x4 a1 = *(const f32x4*)(s + 4);
  bf16x8 p;
  #pragma unroll
  for (int j = 0; j < 4; ++j) {
    p[j]     = (short)f2bf(a0[j]);
    p[j + 4] = (short)f2bf(a1[j]);
  }
  *(bf16x8*)(dst + (size_t)chunk * 8) = p;
}

// ---------------- kernel 1: 256^2 2-barrier/K-tile bf16 MFMA GEMM + per-(row,256-block) top-2 ----------------
// All LDS read addrs collapse to 6 base pointers because (row&7)==(l15&7) for
// every fragment row: addr = base[buf][ks] + {mi,ni}*1024 (compile-time imm).

#define STAGE_A(BUF, KT, H) do {                                                  \
    GLDS16(ga + ((KT)*16384 + (H)*8192),        &lsA[BUF][(H)*8192 + w*512]);     \
    GLDS16(ga + ((KT)*16384 + (H)*8192 + 4096), &lsA[BUF][(H)*8192 + w*512 + 4096]); \
  } while (0)
#define STAGE_B(BUF, KT, H) do {                                                  \
    GLDS16(gb + ((KT)*16384 + (H)*8192),        &lsB[BUF][(H)*8192 + w*512]);     \
    GLDS16(gb + ((KT)*16384 + (H)*8192 + 4096), &lsB[BUF][(H)*8192 + w*512 + 4096]); \
  } while (0)

#define RD_A(MIB, BUF) do {                                                       \
    _Pragma("unroll")                                                             \
    for (int mi_ = 0; mi_ < 4; ++mi_) {                                           \
      aF[mi_][0] = *(const bf16x8*)(A0[BUF] + ((MIB) + mi_) * 1024);              \
      aF[mi_][1] = *(const bf16x8*)(A1[BUF] + ((MIB) + mi_) * 1024);              \
    } } while (0)
#define RD_Bx(DST, NIB, BUF) do {                                                 \
    _Pragma("unroll")                                                             \
    for (int ni_ = 0; ni_ < 2; ++ni_) {                                           \
      DST[ni_][0] = *(const bf16x8*)(B0[BUF] + ((NIB) + ni_) * 1024);             \
      DST[ni_][1] = *(const bf16x8*)(B1[BUF] + ((NIB) + ni_) * 1024);             \
    } } while (0)

#define MMA_Q(MB, NB, AF, BF) do {                                                \
    __builtin_amdgcn_s_setprio(1);                                                \
    _Pragma("unroll")                                                             \
    for (int ks_ = 0; ks_ < 2; ++ks_) {                                           \
      _Pragma("unroll")                                                           \
      for (int mi_ = 0; mi_ < 4; ++mi_) {                                         \
        _Pragma("unroll")                                                         \
        for (int ni_ = 0; ni_ < 2; ++ni_)                                         \
          acc[(MB) + mi_][(NB) + ni_] = __builtin_amdgcn_mfma_f32_16x16x32_bf16(  \
              AF[mi_][ks_], BF[ni_][ks_], acc[(MB) + mi_][(NB) + ni_], 0, 0, 0);  \
      } }                                                                         \
    __builtin_amdgcn_s_setprio(0);                                                \
  } while (0)

#define G8  asm volatile("s_waitcnt vmcnt(8)" ::: "memory")
#define G0  asm volatile("s_waitcnt vmcnt(0)" ::: "memory")
#define NOG do {} while (0)

// One K-tile, 2 barriers total. Cross-wave hazards:
//  barrier#1: all waves' B reads (this tile) complete -> B(t+2) may overwrite lsB[BC]
//             (lgkmcnt(0) first: reads are IN REGISTERS, not just issued)
//  barrier#2: after vmcnt guard -> tile t+1's staged data visible to all waves
// A-recycle (stage A(t+2) over tile t-1's buf) is protected by barrier#2 of t-1.
#define TILE(KT, AC, BC, AN, BN_, DOST, GUARD) do {                               \
    if (DOST) { STAGE_A(AN, (KT) + 2, 0); STAGE_A(AN, (KT) + 2, 1); }             \
    RD_Bx(bF0, 0, BC);                                                            \
    RD_Bx(bF1, 2, BC);                                                            \
    RD_A(0, AC);                                                                  \
    asm volatile("s_waitcnt lgkmcnt(0)" ::: "memory");                            \
    sbar();   /* barrier#1 */                                                     \
    if (DOST) { STAGE_B(BN_, (KT) + 2, 0); STAGE_B(BN_, (KT) + 2, 1); }           \
    MMA_Q(0, 0, aF, bF0);                                                         \
    MMA_Q(0, 2, aF, bF1);                                                         \
    RD_A(4, AC);                                                                  \
    MMA_Q(4, 0, aF, bF0);                                                         \
    MMA_Q(4, 2, aF, bF1);                                                         \
    GUARD;                                                                        \
    sbar();   /* barrier#2 */                                                     \
  } while (0)

__global__ __launch_bounds__(512, 2) void snap_gemm256(const ushort* __restrict__ xs,
                                                       const ushort* __restrict__ cs,
                                                       const float* __restrict__ c2,
                                                       int* __restrict__ cand) {
  __shared__ ushort lsA[3][16384];   // 3-deep A ring (96 KB)
  __shared__ ushort lsB[2][16384];   // 2-deep B (64 KB)

  const int t    = threadIdx.x;
  const int lane = t & 63;
  const int w    = t >> 6;          // 0..7
  const int wm   = w >> 2;          // 0..1
  const int wn   = w & 3;           // 0..3
  const int l15  = lane & 15;
  const int kgrp = lane >> 4;

  // XCD-aware swizzle (bijective: 4096 % 8 == 0)
  const int bid = blockIdx.x;
  const int swz = (bid & 7) * 512 + (bid >> 3);
  const int bm  = swz & 63;
  const int bn  = swz >> 6;

  const ushort* xbase = xs + (size_t)bm * (16 * TCH) * 8;
  const ushort* cbase = cs + (size_t)bn * (16 * TCH) * 8;
  const ushort* ga = xbase + w * 512 + lane * 8;   // per-thread stage src base
  const ushort* gb = cbase + w * 512 + lane * 8;

  // Precomputed LDS read base pointers (ushort units).
  const int sw0  = ( kgrp      ^ (l15 & 7)) * 8;
  const int sw1  = ((4 | kgrp) ^ (l15 & 7)) * 8;
  const int arow = (wm * 128 + l15) * 64;
  const int brow = (wn * 64  + l15) * 64;
  const ushort* A0[3]; const ushort* A1[3];
  const ushort* B0[2]; const ushort* B1[2];
  #pragma unroll
  for (int b = 0; b < 3; ++b) { A0[b] = &lsA[b][arow + sw0]; A1[b] = &lsA[b][arow + sw1]; }
  #pragma unroll
  for (int b = 0; b < 2; ++b) { B0[b] = &lsB[b][brow + sw0]; B1[b] = &lsB[b][brow + sw1]; }

  f32x4 acc[8][4];
  #pragma unroll
  for (int mi = 0; mi < 8; ++mi)
    #pragma unroll
    for (int ni = 0; ni < 4; ++ni)
      acc[mi][ni] = (f32x4){0.f, 0.f, 0.f, 0.f};

  bf16x8 aF[4][2], bF0[2][2], bF1[2][2];

  // ---- prologue: tiles 0 and 1 ----
  STAGE_A(0, 0, 0); STAGE_A(0, 0, 1);
  STAGE_B(0, 0, 0); STAGE_B(0, 0, 1);
  STAGE_A(1, 1, 0); STAGE_A(1, 1, 1);
  STAGE_B(1, 1, 0); STAGE_B(1, 1, 1);
  G8;                  // tile 0 landed; tile 1 may fly
  sbar();

  // Fully unrolled K-loop: bufA = kt%3, bufB = kt&1, nxtA = (kt+2)%3, nxtB = kt&1.
  TILE(0 , 0, 0, 2, 0, 1, G8);
  TILE(1 , 1, 1, 0, 1, 1, G8);
  TILE(2 , 2, 0, 1, 0, 1, G8);
  TILE(3 , 0, 1, 2, 1, 1, G8);
  TILE(4 , 1, 0, 0, 0, 1, G8);
  TILE(5 , 2, 1, 1, 1, 1, G8);
  TILE(6 , 0, 0, 2, 0, 1, G8);
  TILE(7 , 1, 1, 0, 1, 1, G8);
  TILE(8 , 2, 0, 1, 0, 1, G8);
  TILE(9 , 0, 1, 2, 1, 1, G8);
  TILE(10, 1, 0, 0, 0, 1, G8);
  TILE(11, 2, 1, 1, 1, 1, G8);
  TILE(12, 0, 0, 2, 0, 1, G8);
  TILE(13, 1, 1, 0, 1, 1, G8);
  TILE(14, 2, 0, 1, 0, 0, G0);
  TILE(15, 0, 1, 2, 1, 0, NOG);

  __syncthreads();   // full drain before overlaying redbuf on lsA

  // ---- epilogue: per-row top-2 over this block's 256 columns (32-bit keys) ----
  int* red = (int*)&lsA[0][0];   // [4][256][2] i32 = 8 KB
  float c2v[4];
  int   colv[4];
  #pragma unroll
  for (int ni = 0; ni < 4; ++ni) {
    colv[ni] = bn * 256 + wn * 64 + ni * 16 + l15;
    c2v[ni]  = c2[colv[ni]];
  }

  #pragma unroll
  for (int mi = 0; mi < 8; ++mi) {
    #pragma unroll
    for (int r = 0; r < 4; ++r) {
      int a = packKey32(fmaf(-2.0f, acc[mi][0][r], c2v[0]), colv[0]);
      int b = packKey32(fmaf(-2.0f, acc[mi][1][r], c2v[1]), colv[1]);
      int c = packKey32(fmaf(-2.0f, acc[mi][2][r], c2v[2]), colv[2]);
      int d = packKey32(fmaf(-2.0f, acc[mi][3][r], c2v[3]), colv[3]);
      int lo1 = imin(a, b), hi1 = imax(a, b);
      int lo2 = imin(c, d), hi2 = imax(c, d);
      int k1 = imin(lo1, lo2);
      int k2 = imin(imax(lo1, lo2), imin(hi1, hi2));
      #pragma unroll
      for (int m = 1; m < 16; m <<= 1) {
        int o1 = __shfl_xor(k1, m);
        int o2 = __shfl_xor(k2, m);
        int n1 = imin(k1, o1);
        int n2 = imin(imax(k1, o1), imin(k2, o2));
        k1 = n1; k2 = n2;
      }
      if (l15 == 0) {
        int rl = wm * 128 + mi * 16 + kgrp * 4 + r;
        red[(wn * 256 + rl) * 2 + 0] = k1;
        red[(wn * 256 + rl) * 2 + 1] = k2;
      }
    }
  }
  __syncthreads();

  if (t < 256) {
    int k1 = red[(0 * 256 + t) * 2 + 0];
    int k2 = red[(0 * 256 + t) * 2 + 1];
    #pragma unroll
    for (int q = 1; q < 4; ++q) {
      int p1 = red[(q * 256 + t) * 2 + 0];
      int p2 = red[(q * 256 + t) * 2 + 1];
      int n1 = imin(k1, p1);
      int n2 = imin(imax(k1, p1), imin(k2, p2));
      k1 = n1; k2 = n2;
    }
    size_t o = (size_t)(bm * 256 + t) * 128 + (size_t)bn * 2;
    cand[o]     = k1;
    cand[o + 1] = k2;
  }
}

// ---------------- kernel 1 (fallback, known-good structure): on-the-fly 128^2 ----------------
__global__ __launch_bounds__(256) void snap_gemm_slow(const float* __restrict__ x,
                                                      const float* __restrict__ cb,
                                                      const float* __restrict__ c2,
                                                      int* __restrict__ cand) {
  __shared__ ushort lsA[2][8192];
  __shared__ ushort lsB[2][8192];
  __shared__ int redbuf[2][128][2];

  const int t    = threadIdx.x;
  const int lane = t & 63;
  const int wid  = t >> 6;
  const int wm   = wid & 1;
  const int wn   = wid >> 1;
  const int l15  = lane & 15;
  const int kgrp = lane >> 4;

  const int bm = blockIdx.x & 127;
  const int bn = blockIdx.x >> 7;
  const int rowBase = bm * 128;
  const int colBase = bn * 128;

  const float* aptr[4];
  const float* bptr[4];
  int ldsOff[4];
  #pragma unroll
  for (int i = 0; i < 4; ++i) {
    int pc = t + 256 * i;
    int row = pc >> 3;
    int g = (pc & 7) ^ (row & 7);
    aptr[i] = x  + (size_t)(rowBase + row) * DIM + g * 8;
    bptr[i] = cb + (size_t)(colBase + row) * DIM + g * 8;
    ldsOff[i] = pc * 8;
  }

  f32x4 acc[4][4];
  #pragma unroll
  for (int mi = 0; mi < 4; ++mi)
    #pragma unroll
    for (int ni = 0; ni < 4; ++ni)
      acc[mi][ni] = (f32x4){0.f, 0.f, 0.f, 0.f};

  auto STAGE = [&](int buf, int kt) {
    const int kOff = kt * 64;
    #pragma unroll
    for (int i = 0; i < 4; ++i) {
      f32x4 a0 = *(const f32x4*)(aptr[i] + kOff);
      f32x4 a1 = *(const f32x4*)(aptr[i] + kOff + 4);
      f32x4 b0 = *(const f32x4*)(bptr[i] + kOff);
      f32x4 b1 = *(const f32x4*)(bptr[i] + kOff + 4);
      bf16x8 pa, pb;
      #pragma unroll
      for (int j = 0; j < 4; ++j) {
        pa[j]     = (short)f2bf(a0[j]);
        pa[j + 4] = (short)f2bf(a1[j]);
        pb[j]     = (short)f2bf(b0[j]);
        pb[j + 4] = (short)f2bf(b1[j]);
      }
      *(bf16x8*)(&lsA[buf][ldsOff[i]]) = pa;
      *(bf16x8*)(&lsB[buf][ldsOff[i]]) = pb;
    }
  };

  STAGE(0, 0);
  __syncthreads();

  for (int kt = 0; kt < DIM / 64; ++kt) {
    const int cur = kt & 1;
    if (kt < DIM / 64 - 1) STAGE(cur ^ 1, kt + 1);

    const ushort* bA = &lsA[cur][0];
    const ushort* bB = &lsB[cur][0];
    #pragma unroll
    for (int ks = 0; ks < 2; ++ks) {
      const int gidx = ks * 4 + kgrp;
      bf16x8 af[4], bfr[4];
      #pragma unroll
      for (int mi = 0; mi < 4; ++mi) {
        int r_ = wm * 64 + mi * 16 + l15;
        af[mi] = *(const bf16x8*)(bA + (r_ * 8 + (gidx ^ (r_ & 7))) * 8);
      }
      #pragma unroll
      for (int ni = 0; ni < 4; ++ni) {
        int c_ = wn * 64 + ni * 16 + l15;
        bfr[ni] = *(const bf16x8*)(bB + (c_ * 8 + (gidx ^ (c_ & 7))) * 8);
      }
      #pragma unroll
      for (int mi = 0; mi < 4; ++mi)
        #pragma unroll
        for (int ni = 0; ni < 4; ++ni)
          acc[mi][ni] = __builtin_amdgcn_mfma_f32_16x16x32_bf16(af[mi], bfr[ni], acc[mi][ni], 0, 0, 0);
    }
    __syncthreads();
  }

  float c2v[4];
  int   colv[4];
  #pragma unroll
  for (int ni = 0; ni < 4; ++ni) {
    colv[ni] = colBase + wn * 64 + ni * 16 + l15;
    c2v[ni]  = c2[colv[ni]];
  }

  #pragma unroll
  for (int mi = 0; mi < 4; ++mi) {
    #pragma unroll
    for (int r = 0; r < 4; ++r) {
      int a = packKey32(fmaf(-2.0f, acc[mi][0][r], c2v[0]), colv[0]);
      int b = packKey32(fmaf(-2.0f, acc[mi][1][r], c2v[1]), colv[1]);
      int c = packKey32(fmaf(-2.0f, acc[mi][2][r], c2v[2]), colv[2]);
      int d = packKey32(fmaf(-2.0f, acc[mi][3][r], c2v[3]), colv[3]);
      int lo1 = imin(a, b), hi1 = imax(a, b);
      int lo2 = imin(c, d), hi2 = imax(c, d);
      int k1 = imin(lo1, lo2);
      int k2 = imin(imax(lo1, lo2), imin(hi1, hi2));
      #pragma unroll
      for (int m = 1; m < 16; m <<= 1) {
        int o1 = __shfl_xor(k1, m);
        int o2 = __shfl_xor(k2, m);
        int n1 = imin(k1, o1);
        int n2 = imin(imax(k1, o1), imin(k2, o2));
        k1 = n1; k2 = n2;
      }
      if (l15 == 0) {
        int rl = wm * 64 + mi * 16 + kgrp * 4 + r;
        redbuf[wn][rl][0] = k1;
        redbuf[wn][rl][1] = k2;
      }
    }
  }
  __syncthreads();

  if (t < 128) {
    int a1 = redbuf[0][t][0], a2 = redbuf[0][t][1];
    int b1 = redbuf[1][t][0], b2 = redbuf[1][t][1];
    int m1 = imin(a1, b1);
    int m2 = imin(imax(a1, b1), imin(a2, b2));
    size_t o = (size_t)(rowBase + t) * 256 + (size_t)bn * 2;
    cand[o]     = m1;
    cand[o + 1] = m2;
  }
}

// ---------------- kernel 2: exact f64 rerank of candidates within margin of pool-min ----------------
__global__ __launch_bounds__(256) void rerank(const float* __restrict__ x,
                                              const float* __restrict__ cb,
                                              const int* __restrict__ cand,
                                              int* __restrict__ bestidx,
                                              int poolN) {
  const int row = blockIdx.x;
  const int t = threadIdx.x, lane = t & 63, wid = t >> 6;
  __shared__ int    smin[4];
  __shared__ int    gshared;
  __shared__ double dpart[4];
  __shared__ int    cnt;
  __shared__ int    list[64];

  int my = (t < poolN) ? cand[(size_t)row * poolN + t] : 0x7FFFFFFF;
  int k = my;
  #pragma unroll
  for (int off = 32; off; off >>= 1) k = imin(k, __shfl_down(k, off));
  if (lane == 0) smin[wid] = k;
  if (t == 0) cnt = 0;
  __syncthreads();
  if (t == 0) {
    int g = smin[0];
    for (int i = 1; i < 4; ++i) g = imin(g, smin[i]);
    gshared = g;
  }
  __syncthreads();

  const int gq = gshared >> 14;
  if ((my >> 14) <= gq + MARGIN_Q) {
    int p = atomicAdd(&cnt, 1);
    if (p < 64) list[p] = my & 16383;
  }
  __syncthreads();
  int n = cnt; if (n > 64) n = 64;

  uint64_t best = ~0ull;
  const float* xr = x + (size_t)row * DIM;
  for (int i = 0; i < n; ++i) {
    const int cidx = list[i];
    const float* cr = cb + (size_t)cidx * DIM;
    double p = 0.0;
    #pragma unroll
    for (int j = 0; j < 4; ++j) {
      int d = t + 256 * j;
      double diff = (double)xr[d] - (double)cr[d];
      p += diff * diff;
    }
    #pragma unroll
    for (int off = 32; off; off >>= 1) p += __shfl_down(p, off);
    if (lane == 0) dpart[wid] = p;
    __syncthreads();
    if (t == 0) {
      double d2 = dpart[0] + dpart[1] + dpart[2] + dpart[3];
      uint64_t bits = (uint64_t)__double_as_longlong(d2);
      uint64_t key = (bits & ~0x3FFFull) | (uint32_t)cidx;
      if (key < best) best = key;
    }
    __syncthreads();
  }
  if (t == 0) bestidx[row] = (int)(best & 0x3FFFull);
}

// ---------------- kernel 3: gather winning codebook rows ----------------
__global__ __launch_bounds__(256) void gather_rows(const float* __restrict__ cb,
                                                   const int* __restrict__ bestidx,
                                                   float* __restrict__ out) {
  const int row = blockIdx.x;
  const int idx = bestidx[row];
  f32x4 v = *(const f32x4*)(cb + (size_t)idx * DIM + threadIdx.x * 4);
  *(f32x4*)(out + (size_t)row * DIM + threadIdx.x * 4) = v;
}

extern "C" void kernel_launch(void* const* d_in, const int* in_sizes, int n_in,
                              void* d_out, int out_size, void* d_ws, size_t ws_size,
                              hipStream_t stream) {
  const float* x  = (const float*)d_in[0];
  const float* cb = (const float*)d_in[1];
  float* out = (float*)d_out;

  float* c2      = (float*)d_ws;                        // 64 KB
  int*   bestidx = (int*)((char*)d_ws + 64 * 1024);     // 64 KB

  const size_t candBytes = (size_t)NROWS * 128 * 4;     // 8 MB (32-bit keys)
  const size_t needFast  = 128 * 1024 + candBytes;

  c2_kernel<<<NCODES, 256, 0, stream>>>(cb, c2);

  if (ws_size >= needFast) {
    ushort* xs = (ushort*)d_out;                        // 33.5 MB (bf16, tile-blocked+swizzled)
    ushort* cs = xs + (size_t)NROWS * DIM;              // 33.5 MB
    int* cand = (int*)((char*)d_ws + 128 * 1024);

    convert_swz256<<<8192, 256, 0, stream>>>(x,  xs);
    convert_swz256<<<8192, 256, 0, stream>>>(cb, cs);
    snap_gemm256<<<4096, 512, 0, stream>>>(xs, cs, c2, cand);
    rerank<<<NROWS, 256, 0, stream>>>(x, cb, cand, bestidx, 128);
    gather_rows<<<NROWS, 256, 0, stream>>>(cb, bestidx, out);
  } else {
    int* cand = (int*)d_out;
    snap_gemm_slow<<<(NROWS / 128) * (NCODES / 128), 256, 0, stream>>>(x, cb, c2, cand);
    rerank<<<NROWS, 256, 0, stream>>>(x, cb, cand, bestidx, 256);
    gather_rows<<<NROWS, 256, 0, stream>>>(cb, bestidx, out);
  }
}

// Round 8
// 650.761 us; speedup vs baseline: 1.2615x; 1.0162x over previous
//
#include <hip/hip_runtime.h>
#include <hip/hip_bf16.h>
#include <stdint.h>

// x: (4,4096,1024) f32 -> 16384 x 1024 rows; codebook: (16384,1024) f32
#define NROWS  16384
#define NCODES 16384
#define DIM    1024
#define NT     16          // DIM / BK,  BK = 64
#define TCH    2048        // 16B chunks per 256x64 tile
#define MARGIN_Q 52        // quantized margin: 3.0 (bf16 ~20 sigma) + quant slop, in 1/16 units

typedef float f32x4  __attribute__((ext_vector_type(4)));
typedef short bf16x8 __attribute__((ext_vector_type(8)));

__device__ __forceinline__ ushort f2bf(float f) {
  uint32_t u = __float_as_uint(f);
  uint32_t r = u + 0x7FFFu + ((u >> 16) & 1u);
  return (ushort)(r >> 16);
}
__device__ __forceinline__ int imin(int a, int b){ return a < b ? a : b; }
__device__ __forceinline__ int imax(int a, int b){ return a < b ? b : a; }
__device__ __forceinline__ int packKey32(float s, int idx) {
  int q = (int)rintf(s * 16.0f);
  return q * 16384 + idx;
}

#define GLDS16(gp, lp) \
  __builtin_amdgcn_global_load_lds((const __attribute__((address_space(1))) void*)(gp), \
                                   (__attribute__((address_space(3))) void*)(lp), 16, 0, 0)

__device__ __forceinline__ void sbar() {
  asm volatile("" ::: "memory");
  __builtin_amdgcn_s_barrier();
  asm volatile("" ::: "memory");
}

// ---------------- kernel 0: c2[c] = sum(codebook[c]^2) ----------------
__global__ __launch_bounds__(256) void c2_kernel(const float* __restrict__ cb,
                                                 float* __restrict__ c2) {
  const int code = blockIdx.x;
  const int t = threadIdx.x, lane = t & 63, wid = t >> 6;
  f32x4 v = *(const f32x4*)(cb + (size_t)code * DIM + t * 4);
  float s = v[0]*v[0] + v[1]*v[1] + v[2]*v[2] + v[3]*v[3];
  #pragma unroll
  for (int off = 32; off; off >>= 1) s += __shfl_down(s, off);
  __shared__ float part[4];
  if (lane == 0) part[wid] = s;
  __syncthreads();
  if (t == 0) c2[code] = part[0] + part[1] + part[2] + part[3];
}

// ---------------- kernel 0b: f32 -> bf16, pre-swizzled 256x64-tile-blocked layout ----------------
__global__ __launch_bounds__(256) void convert_swz256(const float* __restrict__ src,
                                                      ushort* __restrict__ dst) {
  const int chunk = blockIdx.x * 256 + threadIdx.x;   // [0, 64*16*2048)
  const int pc  = chunk & 2047;
  const int kt  = (chunk >> 11) & 15;
  const int m   = chunk >> 15;
  const int row = pc >> 3;
  const int g   = (pc & 7) ^ (row & 7);
  const float* s = src + (size_t)(m * 256 + row) * DIM + kt * 64 + g * 8;
  f32x4 a0 = *(const f32x4*)s;
  f32x4 a1 = *(const f32x4*)(s + 4);
  bf16x8 p;
  #pragma unroll
  for (int j = 0; j < 4; ++j) {
    p[j]     = (short)f2bf(a0[j]);
    p[j + 4] = (short)f2bf(a1[j]);
  }
  *(bf16x8*)(dst + (size_t)chunk * 8) = p;
}

// ---------------- kernel 1: 256^2 bf16 MFMA GEMM, read/MFMA-overlapped + per-(row,256-block) top-2 ----------------
// All LDS read addrs collapse to 6 base pointers because (row&7)==(l15&7) for
// every fragment row: addr = base[buf][ks] + {mi,ni}*1024 (compile-time imm).

#define STAGE_A(BUF, KT, H) do {                                                  \
    GLDS16(ga + ((KT)*16384 + (H)*8192),        &lsA[BUF][(H)*8192 + w*512]);     \
    GLDS16(ga + ((KT)*16384 + (H)*8192 + 4096), &lsA[BUF][(H)*8192 + w*512 + 4096]); \
  } while (0)
#define STAGE_B(BUF, KT, H) do {                                                  \
    GLDS16(gb + ((KT)*16384 + (H)*8192),        &lsB[BUF][(H)*8192 + w*512]);     \
    GLDS16(gb + ((KT)*16384 + (H)*8192 + 4096), &lsB[BUF][(H)*8192 + w*512 + 4096]); \
  } while (0)

#define RD_A(MIB, BUF) do {                                                       \
    _Pragma("unroll")                                                             \
    for (int mi_ = 0; mi_ < 4; ++mi_) {                                           \
      aF[mi_][0] = *(const bf16x8*)(A0[BUF] + ((MIB) + mi_) * 1024);              \
      aF[mi_][1] = *(const bf16x8*)(A1[BUF] + ((MIB) + mi_) * 1024);              \
    } } while (0)
#define RD_Bx(DST, NIB, BUF) do {                                                 \
    _Pragma("unroll")                                                             \
    for (int ni_ = 0; ni_ < 2; ++ni_) {                                           \
      DST[ni_][0] = *(const bf16x8*)(B0[BUF] + ((NIB) + ni_) * 1024);             \
      DST[ni_][1] = *(const bf16x8*)(B1[BUF] + ((NIB) + ni_) * 1024);             \
    } } while (0)

#define MMA_Q(MB, NB, AF, BF) do {                                                \
    __builtin_amdgcn_s_setprio(1);                                                \
    _Pragma("unroll")                                                             \
    for (int ks_ = 0; ks_ < 2; ++ks_) {                                           \
      _Pragma("unroll")                                                           \
      for (int mi_ = 0; mi_ < 4; ++mi_) {                                         \
        _Pragma("unroll")                                                         \
        for (int ni_ = 0; ni_ < 2; ++ni_)                                         \
          acc[(MB) + mi_][(NB) + ni_] = __builtin_amdgcn_mfma_f32_16x16x32_bf16(  \
              AF[mi_][ks_], BF[ni_][ks_], acc[(MB) + mi_][(NB) + ni_], 0, 0, 0);  \
      } }                                                                         \
    __builtin_amdgcn_s_setprio(0);                                                \
  } while (0)

#define G8  asm volatile("s_waitcnt vmcnt(8)" ::: "memory")
#define G0  asm volatile("s_waitcnt vmcnt(0)" ::: "memory")
#define NOG do {} while (0)

// One K-tile, 2 barriers. KEY CHANGE vs R7: only the 8 B-reads drain before
// barrier#1; the 16 A-reads are issued AFTER it, interleaved with the 64 MFMAs
// (compiler inserts fine-grained lgkmcnt) -> LDS read pipe overlaps MFMA pipe.
// Hazards:
//  barrier#1 (after B-only lgkm drain): B(t+2) may overwrite lsB[BC].
//  barrier#2 (after lgkm(0), free in steady state, + vmcnt guard):
//    A-reads of tile t retired -> A(t+2) stage next tile may overwrite lsA ring;
//    tile t+1's staged data landed (vmcnt(8), issue-order semantics).
#define TILE(KT, AC, BC, AN, BN_, DOST, GUARD) do {                               \
    RD_Bx(bF0, 0, BC);                                                            \
    RD_Bx(bF1, 2, BC);                                                            \
    asm volatile("s_waitcnt lgkmcnt(0)" ::: "memory");                            \
    sbar();   /* barrier#1 */                                                     \
    if (DOST) { STAGE_A(AN, (KT) + 2, 0); STAGE_A(AN, (KT) + 2, 1);               \
                STAGE_B(BN_, (KT) + 2, 0); STAGE_B(BN_, (KT) + 2, 1); }           \
    RD_A(0, AC);                                                                  \
    MMA_Q(0, 0, aF, bF0);                                                         \
    MMA_Q(0, 2, aF, bF1);                                                         \
    RD_A(4, AC);                                                                  \
    MMA_Q(4, 0, aF, bF0);                                                         \
    MMA_Q(4, 2, aF, bF1);                                                         \
    asm volatile("s_waitcnt lgkmcnt(0)" ::: "memory");                            \
    GUARD;                                                                        \
    sbar();   /* barrier#2 */                                                     \
  } while (0)

__global__ __launch_bounds__(512, 2) void snap_gemm256(const ushort* __restrict__ xs,
                                                       const ushort* __restrict__ cs,
                                                       const float* __restrict__ c2,
                                                       int* __restrict__ cand) {
  __shared__ ushort lsA[3][16384];   // 3-deep A ring (96 KB)
  __shared__ ushort lsB[2][16384];   // 2-deep B (64 KB)

  const int t    = threadIdx.x;
  const int lane = t & 63;
  const int w    = t >> 6;          // 0..7
  const int wm   = w >> 2;          // 0..1
  const int wn   = w & 3;           // 0..3
  const int l15  = lane & 15;
  const int kgrp = lane >> 4;

  // XCD-aware swizzle (bijective: 4096 % 8 == 0)
  const int bid = blockIdx.x;
  const int swz = (bid & 7) * 512 + (bid >> 3);
  const int bm  = swz & 63;
  const int bn  = swz >> 6;

  const ushort* xbase = xs + (size_t)bm * (16 * TCH) * 8;
  const ushort* cbase = cs + (size_t)bn * (16 * TCH) * 8;
  const ushort* ga = xbase + w * 512 + lane * 8;   // per-thread stage src base
  const ushort* gb = cbase + w * 512 + lane * 8;

  // Precomputed LDS read base pointers (ushort units).
  const int sw0  = ( kgrp      ^ (l15 & 7)) * 8;
  const int sw1  = ((4 | kgrp) ^ (l15 & 7)) * 8;
  const int arow = (wm * 128 + l15) * 64;
  const int brow = (wn * 64  + l15) * 64;
  const ushort* A0[3]; const ushort* A1[3];
  const ushort* B0[2]; const ushort* B1[2];
  #pragma unroll
  for (int b = 0; b < 3; ++b) { A0[b] = &lsA[b][arow + sw0]; A1[b] = &lsA[b][arow + sw1]; }
  #pragma unroll
  for (int b = 0; b < 2; ++b) { B0[b] = &lsB[b][brow + sw0]; B1[b] = &lsB[b][brow + sw1]; }

  f32x4 acc[8][4];
  #pragma unroll
  for (int mi = 0; mi < 8; ++mi)
    #pragma unroll
    for (int ni = 0; ni < 4; ++ni)
      acc[mi][ni] = (f32x4){0.f, 0.f, 0.f, 0.f};

  bf16x8 aF[4][2], bF0[2][2], bF1[2][2];

  // ---- prologue: tiles 0 and 1 ----
  STAGE_A(0, 0, 0); STAGE_A(0, 0, 1);
  STAGE_B(0, 0, 0); STAGE_B(0, 0, 1);
  STAGE_A(1, 1, 0); STAGE_A(1, 1, 1);
  STAGE_B(1, 1, 0); STAGE_B(1, 1, 1);
  G8;                  // tile 0 landed; tile 1 may fly
  sbar();

  // Fully unrolled K-loop: bufA = kt%3, bufB = kt&1, nxtA = (kt+2)%3, nxtB = kt&1.
  TILE(0 , 0, 0, 2, 0, 1, G8);
  TILE(1 , 1, 1, 0, 1, 1, G8);
  TILE(2 , 2, 0, 1, 0, 1, G8);
  TILE(3 , 0, 1, 2, 1, 1, G8);
  TILE(4 , 1, 0, 0, 0, 1, G8);
  TILE(5 , 2, 1, 1, 1, 1, G8);
  TILE(6 , 0, 0, 2, 0, 1, G8);
  TILE(7 , 1, 1, 0, 1, 1, G8);
  TILE(8 , 2, 0, 1, 0, 1, G8);
  TILE(9 , 0, 1, 2, 1, 1, G8);
  TILE(10, 1, 0, 0, 0, 1, G8);
  TILE(11, 2, 1, 1, 1, 1, G8);
  TILE(12, 0, 0, 2, 0, 1, G8);
  TILE(13, 1, 1, 0, 1, 1, G8);
  TILE(14, 2, 0, 1, 0, 0, G0);
  TILE(15, 0, 1, 2, 1, 0, NOG);

  __syncthreads();   // full drain before overlaying redbuf on lsA

  // ---- epilogue: per-row top-2 over this block's 256 columns (32-bit keys) ----
  int* red = (int*)&lsA[0][0];   // [4][256][2] i32 = 8 KB
  float c2v[4];
  int   colv[4];
  #pragma unroll
  for (int ni = 0; ni < 4; ++ni) {
    colv[ni] = bn * 256 + wn * 64 + ni * 16 + l15;
    c2v[ni]  = c2[colv[ni]];
  }

  #pragma unroll
  for (int mi = 0; mi < 8; ++mi) {
    #pragma unroll
    for (int r = 0; r < 4; ++r) {
      int a = packKey32(fmaf(-2.0f, acc[mi][0][r], c2v[0]), colv[0]);
      int b = packKey32(fmaf(-2.0f, acc[mi][1][r], c2v[1]), colv[1]);
      int c = packKey32(fmaf(-2.0f, acc[mi][2][r], c2v[2]), colv[2]);
      int d = packKey32(fmaf(-2.0f, acc[mi][3][r], c2v[3]), colv[3]);
      int lo1 = imin(a, b), hi1 = imax(a, b);
      int lo2 = imin(c, d), hi2 = imax(c, d);
      int k1 = imin(lo1, lo2);
      int k2 = imin(imax(lo1, lo2), imin(hi1, hi2));
      #pragma unroll
      for (int m = 1; m < 16; m <<= 1) {
        int o1 = __shfl_xor(k1, m);
        int o2 = __shfl_xor(k2, m);
        int n1 = imin(k1, o1);
        int n2 = imin(imax(k1, o1), imin(k2, o2));
        k1 = n1; k2 = n2;
      }
      if (l15 == 0) {
        int rl = wm * 128 + mi * 16 + kgrp * 4 + r;
        red[(wn * 256 + rl) * 2 + 0] = k1;
        red[(wn * 256 + rl) * 2 + 1] = k2;
      }
    }
  }
  __syncthreads();

  if (t < 256) {
    int k1 = red[(0 * 256 + t) * 2 + 0];
    int k2 = red[(0 * 256 + t) * 2 + 1];
    #pragma unroll
    for (int q = 1; q < 4; ++q) {
      int p1 = red[(q * 256 + t) * 2 + 0];
      int p2 = red[(q * 256 + t) * 2 + 1];
      int n1 = imin(k1, p1);
      int n2 = imin(imax(k1, p1), imin(k2, p2));
      k1 = n1; k2 = n2;
    }
    size_t o = (size_t)(bm * 256 + t) * 128 + (size_t)bn * 2;
    cand[o]     = k1;
    cand[o + 1] = k2;
  }
}

// ---------------- kernel 1 (fallback, known-good structure): on-the-fly 128^2 ----------------
__global__ __launch_bounds__(256) void snap_gemm_slow(const float* __restrict__ x,
                                                      const float* __restrict__ cb,
                                                      const float* __restrict__ c2,
                                                      int* __restrict__ cand) {
  __shared__ ushort lsA[2][8192];
  __shared__ ushort lsB[2][8192];
  __shared__ int redbuf[2][128][2];

  const int t    = threadIdx.x;
  const int lane = t & 63;
  const int wid  = t >> 6;
  const int wm   = wid & 1;
  const int wn   = wid >> 1;
  const int l15  = lane & 15;
  const int kgrp = lane >> 4;

  const int bm = blockIdx.x & 127;
  const int bn = blockIdx.x >> 7;
  const int rowBase = bm * 128;
  const int colBase = bn * 128;

  const float* aptr[4];
  const float* bptr[4];
  int ldsOff[4];
  #pragma unroll
  for (int i = 0; i < 4; ++i) {
    int pc = t + 256 * i;
    int row = pc >> 3;
    int g = (pc & 7) ^ (row & 7);
    aptr[i] = x  + (size_t)(rowBase + row) * DIM + g * 8;
    bptr[i] = cb + (size_t)(colBase + row) * DIM + g * 8;
    ldsOff[i] = pc * 8;
  }

  f32x4 acc[4][4];
  #pragma unroll
  for (int mi = 0; mi < 4; ++mi)
    #pragma unroll
    for (int ni = 0; ni < 4; ++ni)
      acc[mi][ni] = (f32x4){0.f, 0.f, 0.f, 0.f};

  auto STAGE = [&](int buf, int kt) {
    const int kOff = kt * 64;
    #pragma unroll
    for (int i = 0; i < 4; ++i) {
      f32x4 a0 = *(const f32x4*)(aptr[i] + kOff);
      f32x4 a1 = *(const f32x4*)(aptr[i] + kOff + 4);
      f32x4 b0 = *(const f32x4*)(bptr[i] + kOff);
      f32x4 b1 = *(const f32x4*)(bptr[i] + kOff + 4);
      bf16x8 pa, pb;
      #pragma unroll
      for (int j = 0; j < 4; ++j) {
        pa[j]     = (short)f2bf(a0[j]);
        pa[j + 4] = (short)f2bf(a1[j]);
        pb[j]     = (short)f2bf(b0[j]);
        pb[j + 4] = (short)f2bf(b1[j]);
      }
      *(bf16x8*)(&lsA[buf][ldsOff[i]]) = pa;
      *(bf16x8*)(&lsB[buf][ldsOff[i]]) = pb;
    }
  };

  STAGE(0, 0);
  __syncthreads();

  for (int kt = 0; kt < DIM / 64; ++kt) {
    const int cur = kt & 1;
    if (kt < DIM / 64 - 1) STAGE(cur ^ 1, kt + 1);

    const ushort* bA = &lsA[cur][0];
    const ushort* bB = &lsB[cur][0];
    #pragma unroll
    for (int ks = 0; ks < 2; ++ks) {
      const int gidx = ks * 4 + kgrp;
      bf16x8 af[4], bfr[4];
      #pragma unroll
      for (int mi = 0; mi < 4; ++mi) {
        int r_ = wm * 64 + mi * 16 + l15;
        af[mi] = *(const bf16x8*)(bA + (r_ * 8 + (gidx ^ (r_ & 7))) * 8);
      }
      #pragma unroll
      for (int ni = 0; ni < 4; ++ni) {
        int c_ = wn * 64 + ni * 16 + l15;
        bfr[ni] = *(const bf16x8*)(bB + (c_ * 8 + (gidx ^ (c_ & 7))) * 8);
      }
      #pragma unroll
      for (int mi = 0; mi < 4; ++mi)
        #pragma unroll
        for (int ni = 0; ni < 4; ++ni)
          acc[mi][ni] = __builtin_amdgcn_mfma_f32_16x16x32_bf16(af[mi], bfr[ni], acc[mi][ni], 0, 0, 0);
    }
    __syncthreads();
  }

  float c2v[4];
  int   colv[4];
  #pragma unroll
  for (int ni = 0; ni < 4; ++ni) {
    colv[ni] = colBase + wn * 64 + ni * 16 + l15;
    c2v[ni]  = c2[colv[ni]];
  }

  #pragma unroll
  for (int mi = 0; mi < 4; ++mi) {
    #pragma unroll
    for (int r = 0; r < 4; ++r) {
      int a = packKey32(fmaf(-2.0f, acc[mi][0][r], c2v[0]), colv[0]);
      int b = packKey32(fmaf(-2.0f, acc[mi][1][r], c2v[1]), colv[1]);
      int c = packKey32(fmaf(-2.0f, acc[mi][2][r], c2v[2]), colv[2]);
      int d = packKey32(fmaf(-2.0f, acc[mi][3][r], c2v[3]), colv[3]);
      int lo1 = imin(a, b), hi1 = imax(a, b);
      int lo2 = imin(c, d), hi2 = imax(c, d);
      int k1 = imin(lo1, lo2);
      int k2 = imin(imax(lo1, lo2), imin(hi1, hi2));
      #pragma unroll
      for (int m = 1; m < 16; m <<= 1) {
        int o1 = __shfl_xor(k1, m);
        int o2 = __shfl_xor(k2, m);
        int n1 = imin(k1, o1);
        int n2 = imin(imax(k1, o1), imin(k2, o2));
        k1 = n1; k2 = n2;
      }
      if (l15 == 0) {
        int rl = wm * 64 + mi * 16 + kgrp * 4 + r;
        redbuf[wn][rl][0] = k1;
        redbuf[wn][rl][1] = k2;
      }
    }
  }
  __syncthreads();

  if (t < 128) {
    int a1 = redbuf[0][t][0], a2 = redbuf[0][t][1];
    int b1 = redbuf[1][t][0], b2 = redbuf[1][t][1];
    int m1 = imin(a1, b1);
    int m2 = imin(imax(a1, b1), imin(a2, b2));
    size_t o = (size_t)(rowBase + t) * 256 + (size_t)bn * 2;
    cand[o]     = m1;
    cand[o + 1] = m2;
  }
}

// ---------------- kernel 2: exact f64 rerank of candidates within margin of pool-min ----------------
__global__ __launch_bounds__(256) void rerank(const float* __restrict__ x,
                                              const float* __restrict__ cb,
                                              const int* __restrict__ cand,
                                              int* __restrict__ bestidx,
                                              int poolN) {
  const int row = blockIdx.x;
  const int t = threadIdx.x, lane = t & 63, wid = t >> 6;
  __shared__ int    smin[4];
  __shared__ int    gshared;
  __shared__ double dpart[4];
  __shared__ int    cnt;
  __shared__ int    list[64];

  int my = (t < poolN) ? cand[(size_t)row * poolN + t] : 0x7FFFFFFF;
  int k = my;
  #pragma unroll
  for (int off = 32; off; off >>= 1) k = imin(k, __shfl_down(k, off));
  if (lane == 0) smin[wid] = k;
  if (t == 0) cnt = 0;
  __syncthreads();
  if (t == 0) {
    int g = smin[0];
    for (int i = 1; i < 4; ++i) g = imin(g, smin[i]);
    gshared = g;
  }
  __syncthreads();

  const int gq = gshared >> 14;
  if ((my >> 14) <= gq + MARGIN_Q) {
    int p = atomicAdd(&cnt, 1);
    if (p < 64) list[p] = my & 16383;
  }
  __syncthreads();
  int n = cnt; if (n > 64) n = 64;

  uint64_t best = ~0ull;
  const float* xr = x + (size_t)row * DIM;
  for (int i = 0; i < n; ++i) {
    const int cidx = list[i];
    const float* cr = cb + (size_t)cidx * DIM;
    double p = 0.0;
    #pragma unroll
    for (int j = 0; j < 4; ++j) {
      int d = t + 256 * j;
      double diff = (double)xr[d] - (double)cr[d];
      p += diff * diff;
    }
    #pragma unroll
    for (int off = 32; off; off >>= 1) p += __shfl_down(p, off);
    if (lane == 0) dpart[wid] = p;
    __syncthreads();
    if (t == 0) {
      double d2 = dpart[0] + dpart[1] + dpart[2] + dpart[3];
      uint64_t bits = (uint64_t)__double_as_longlong(d2);
      uint64_t key = (bits & ~0x3FFFull) | (uint32_t)cidx;
      if (key < best) best = key;
    }
    __syncthreads();
  }
  if (t == 0) bestidx[row] = (int)(best & 0x3FFFull);
}

// ---------------- kernel 3: gather winning codebook rows ----------------
__global__ __launch_bounds__(256) void gather_rows(const float* __restrict__ cb,
                                                   const int* __restrict__ bestidx,
                                                   float* __restrict__ out) {
  const int row = blockIdx.x;
  const int idx = bestidx[row];
  f32x4 v = *(const f32x4*)(cb + (size_t)idx * DIM + threadIdx.x * 4);
  *(f32x4*)(out + (size_t)row * DIM + threadIdx.x * 4) = v;
}

extern "C" void kernel_launch(void* const* d_in, const int* in_sizes, int n_in,
                              void* d_out, int out_size, void* d_ws, size_t ws_size,
                              hipStream_t stream) {
  const float* x  = (const float*)d_in[0];
  const float* cb = (const float*)d_in[1];
  float* out = (float*)d_out;

  float* c2      = (float*)d_ws;                        // 64 KB
  int*   bestidx = (int*)((char*)d_ws + 64 * 1024);     // 64 KB

  const size_t candBytes = (size_t)NROWS * 128 * 4;     // 8 MB (32-bit keys)
  const size_t needFast  = 128 * 1024 + candBytes;

  c2_kernel<<<NCODES, 256, 0, stream>>>(cb, c2);

  if (ws_size >= needFast) {
    ushort* xs = (ushort*)d_out;                        // 33.5 MB (bf16, tile-blocked+swizzled)
    ushort* cs = xs + (size_t)NROWS * DIM;              // 33.5 MB
    int* cand = (int*)((char*)d_ws + 128 * 1024);

    convert_swz256<<<8192, 256, 0, stream>>>(x,  xs);
    convert_swz256<<<8192, 256, 0, stream>>>(cb, cs);
    snap_gemm256<<<4096, 512, 0, stream>>>(xs, cs, c2, cand);
    rerank<<<NROWS, 256, 0, stream>>>(x, cb, cand, bestidx, 128);
    gather_rows<<<NROWS, 256, 0, stream>>>(cb, bestidx, out);
  } else {
    int* cand = (int*)d_out;
    snap_gemm_slow<<<(NROWS / 128) * (NCODES / 128), 256, 0, stream>>>(x, cb, c2, cand);
    rerank<<<NROWS, 256, 0, stream>>>(x, cb, cand, bestidx, 256);
    gather_rows<<<NROWS, 256, 0, stream>>>(cb, bestidx, out);
  }
}

// Round 9
// 645.179 us; speedup vs baseline: 1.2724x; 1.0087x over previous
//
#include <hip/hip_runtime.h>
#include <hip/hip_bf16.h>
#include <hip/hip_fp8.h>
#include <stdint.h>

// x: (4,4096,1024) f32 -> 16384 x 1024 rows; codebook: (16384,1024) f32
#define NROWS  16384
#define NCODES 16384
#define DIM    1024
#define NT     16           // DIM / BK,  BK = 64
#define MARGIN_Q 514        // fp8 path: 32.1 in 1/16 units (~10 sigma of fp8 score noise)

typedef float f32x4  __attribute__((ext_vector_type(4)));
typedef short bf16x8 __attribute__((ext_vector_type(8)));
typedef unsigned char uchar;

__device__ __forceinline__ ushort f2bf(float f) {
  uint32_t u = __float_as_uint(f);
  uint32_t r = u + 0x7FFFu + ((u >> 16) & 1u);
  return (ushort)(r >> 16);
}
__device__ __forceinline__ int imin(int a, int b){ return a < b ? a : b; }
__device__ __forceinline__ int imax(int a, int b){ return a < b ? b : a; }
__device__ __forceinline__ int packKey32(float s, int idx) {
  int q = (int)rintf(s * 16.0f);
  return q * 16384 + idx;
}

#define GLDS16(gp, lp) \
  __builtin_amdgcn_global_load_lds((const __attribute__((address_space(1))) void*)(gp), \
                                   (__attribute__((address_space(3))) void*)(lp), 16, 0, 0)

__device__ __forceinline__ void sbar() {
  asm volatile("" ::: "memory");
  __builtin_amdgcn_s_barrier();
  asm volatile("" ::: "memory");
}

// ---------------- kernel 0: c2[c] = sum(codebook[c]^2) (exact f32) ----------------
__global__ __launch_bounds__(256) void c2_kernel(const float* __restrict__ cb,
                                                 float* __restrict__ c2) {
  const int code = blockIdx.x;
  const int t = threadIdx.x, lane = t & 63, wid = t >> 6;
  f32x4 v = *(const f32x4*)(cb + (size_t)code * DIM + t * 4);
  float s = v[0]*v[0] + v[1]*v[1] + v[2]*v[2] + v[3]*v[3];
  #pragma unroll
  for (int off = 32; off; off >>= 1) s += __shfl_down(s, off);
  __shared__ float part[4];
  if (lane == 0) part[wid] = s;
  __syncthreads();
  if (t == 0) c2[code] = part[0] + part[1] + part[2] + part[3];
}

// ---------------- kernel 0b: f32 -> fp8 e4m3, pre-swizzled 256x64-tile layout ----------------
// Tile (m,kt) = 16 KB: row (0..255) x 64 k-bytes. 8-byte slots s=0..7 per row,
// phys slot = s ^ (row&7). A 16B chunk p (phys slots 2p,2p+1) holds logical
// chunk c = p ^ ((row&7)>>1), with 8B halves swapped when row is odd.
__global__ __launch_bounds__(256) void convert_fp8_swz(const float* __restrict__ src,
                                                       uchar* __restrict__ dst) {
  const int chunk = blockIdx.x * 256 + threadIdx.x;   // [0, 2^20)
  const int p   = chunk & 3;
  const int row = (chunk >> 2) & 255;
  const int kt  = (chunk >> 10) & 15;
  const int m   = chunk >> 14;
  const int c   = p ^ ((row & 7) >> 1);
  const float* s = src + (size_t)(m * 256 + row) * DIM + kt * 64 + c * 16;
  uchar b[16];
  #pragma unroll
  for (int j = 0; j < 16; ++j) {
    __hip_fp8_e4m3 h(s[j]);
    b[j] = h.__x;
  }
  uint64_t lo = 0, hi = 0;
  #pragma unroll
  for (int j = 0; j < 8; ++j) { lo |= (uint64_t)b[j] << (8 * j); hi |= (uint64_t)b[j + 8] << (8 * j); }
  uint64_t* o = (uint64_t*)(dst + (size_t)chunk * 16);
  if (row & 1) { o[0] = hi; o[1] = lo; }
  else         { o[0] = lo; o[1] = hi; }
}

// ---------------- kernel 1: 256^2 fp8 MFMA GEMM (R8 schedule) + per-(row,256-block) top-2 ----------------
// Read addr: row*64 + ((ks*4+kgrp)^(row&7))*8 bytes; (row&7)==(l15&7) for all
// fragment rows -> 2 base ptrs per buffer + mi*1024 compile-time offsets.

#define STAGE_A(BUF, KT) do {                                                     \
    GLDS16(ga + (KT)*16384,        &lsA[BUF][w*1024]);                            \
    GLDS16(ga + (KT)*16384 + 8192, &lsA[BUF][w*1024 + 8192]);                     \
  } while (0)
#define STAGE_B(BUF, KT) do {                                                     \
    GLDS16(gb + (KT)*16384,        &lsB[BUF][w*1024]);                            \
    GLDS16(gb + (KT)*16384 + 8192, &lsB[BUF][w*1024 + 8192]);                     \
  } while (0)

#define RD_A(MIB, BUF) do {                                                       \
    _Pragma("unroll")                                                             \
    for (int mi_ = 0; mi_ < 4; ++mi_) {                                           \
      aF[mi_][0] = *(const long*)(A0[BUF] + ((MIB) + mi_) * 1024);                \
      aF[mi_][1] = *(const long*)(A1[BUF] + ((MIB) + mi_) * 1024);                \
    } } while (0)
#define RD_Bx(DST, NIB, BUF) do {                                                 \
    _Pragma("unroll")                                                             \
    for (int ni_ = 0; ni_ < 2; ++ni_) {                                           \
      DST[ni_][0] = *(const long*)(B0[BUF] + ((NIB) + ni_) * 1024);               \
      DST[ni_][1] = *(const long*)(B1[BUF] + ((NIB) + ni_) * 1024);               \
    } } while (0)

#define MMA_Q(MB, NB, AF, BF) do {                                                \
    __builtin_amdgcn_s_setprio(1);                                                \
    _Pragma("unroll")                                                             \
    for (int ks_ = 0; ks_ < 2; ++ks_) {                                           \
      _Pragma("unroll")                                                           \
      for (int mi_ = 0; mi_ < 4; ++mi_) {                                         \
        _Pragma("unroll")                                                         \
        for (int ni_ = 0; ni_ < 2; ++ni_)                                         \
          acc[(MB) + mi_][(NB) + ni_] = __builtin_amdgcn_mfma_f32_16x16x32_fp8_fp8( \
              AF[mi_][ks_], BF[ni_][ks_], acc[(MB) + mi_][(NB) + ni_], 0, 0, 0);  \
      } }                                                                         \
    __builtin_amdgcn_s_setprio(0);                                                \
  } while (0)

#define G4  asm volatile("s_waitcnt vmcnt(4)" ::: "memory")
#define G0  asm volatile("s_waitcnt vmcnt(0)" ::: "memory")
#define NOG do {} while (0)

// R8 schedule: B-reads drain before barrier#1 (B-recycle hazard only); A-reads
// interleave with MFMAs after it. 4 staging loads per K-tile; vmcnt(4) guard.
#define TILE(KT, AC, BC, AN, BN_, DOST, GUARD) do {                               \
    RD_Bx(bF0, 0, BC);                                                            \
    RD_Bx(bF1, 2, BC);                                                            \
    asm volatile("s_waitcnt lgkmcnt(0)" ::: "memory");                            \
    sbar();   /* barrier#1 */                                                     \
    if (DOST) { STAGE_A(AN, (KT) + 2); STAGE_B(BN_, (KT) + 2); }                  \
    RD_A(0, AC);                                                                  \
    MMA_Q(0, 0, aF, bF0);                                                         \
    MMA_Q(0, 2, aF, bF1);                                                         \
    RD_A(4, AC);                                                                  \
    MMA_Q(4, 0, aF, bF0);                                                         \
    MMA_Q(4, 2, aF, bF1);                                                         \
    asm volatile("s_waitcnt lgkmcnt(0)" ::: "memory");                            \
    GUARD;                                                                        \
    sbar();   /* barrier#2 */                                                     \
  } while (0)

__global__ __launch_bounds__(512, 2) void snap_gemm256(const uchar* __restrict__ xs,
                                                       const uchar* __restrict__ cs,
                                                       const float* __restrict__ c2,
                                                       int* __restrict__ cand) {
  __shared__ uchar lsA[3][16384];   // 3-deep A ring (48 KB)
  __shared__ uchar lsB[2][16384];   // 2-deep B (32 KB)

  const int t    = threadIdx.x;
  const int lane = t & 63;
  const int w    = t >> 6;          // 0..7
  const int wm   = w >> 2;          // 0..1
  const int wn   = w & 3;           // 0..3
  const int l15  = lane & 15;
  const int kgrp = lane >> 4;

  // XCD-aware swizzle (bijective: 4096 % 8 == 0)
  const int bid = blockIdx.x;
  const int swz = (bid & 7) * 512 + (bid >> 3);
  const int bm  = swz & 63;
  const int bn  = swz >> 6;

  const uchar* ga = xs + (size_t)bm * 16 * 16384 + w * 1024 + lane * 16;
  const uchar* gb = cs + (size_t)bn * 16 * 16384 + w * 1024 + lane * 16;

  // Precomputed LDS read base pointers (bytes).
  const int sw0  = (( kgrp)      ^ (l15 & 7)) * 8;
  const int sw1  = ((4 | kgrp)   ^ (l15 & 7)) * 8;
  const int arow = (wm * 128 + l15) * 64;
  const int brow = (wn * 64  + l15) * 64;
  const uchar* A0[3]; const uchar* A1[3];
  const uchar* B0[2]; const uchar* B1[2];
  #pragma unroll
  for (int b = 0; b < 3; ++b) { A0[b] = &lsA[b][arow + sw0]; A1[b] = &lsA[b][arow + sw1]; }
  #pragma unroll
  for (int b = 0; b < 2; ++b) { B0[b] = &lsB[b][brow + sw0]; B1[b] = &lsB[b][brow + sw1]; }

  f32x4 acc[8][4];
  #pragma unroll
  for (int mi = 0; mi < 8; ++mi)
    #pragma unroll
    for (int ni = 0; ni < 4; ++ni)
      acc[mi][ni] = (f32x4){0.f, 0.f, 0.f, 0.f};

  long aF[4][2], bF0[2][2], bF1[2][2];

  // ---- prologue: tiles 0 and 1 (4 loads each) ----
  STAGE_A(0, 0); STAGE_B(0, 0);
  STAGE_A(1, 1); STAGE_B(1, 1);
  G4;                  // tile 0 landed; tile 1 may fly
  sbar();

  // Fully unrolled K-loop: bufA = kt%3, bufB = kt&1, nxtA = (kt+2)%3, nxtB = kt&1.
  TILE(0 , 0, 0, 2, 0, 1, G4);
  TILE(1 , 1, 1, 0, 1, 1, G4);
  TILE(2 , 2, 0, 1, 0, 1, G4);
  TILE(3 , 0, 1, 2, 1, 1, G4);
  TILE(4 , 1, 0, 0, 0, 1, G4);
  TILE(5 , 2, 1, 1, 1, 1, G4);
  TILE(6 , 0, 0, 2, 0, 1, G4);
  TILE(7 , 1, 1, 0, 1, 1, G4);
  TILE(8 , 2, 0, 1, 0, 1, G4);
  TILE(9 , 0, 1, 2, 1, 1, G4);
  TILE(10, 1, 0, 0, 0, 1, G4);
  TILE(11, 2, 1, 1, 1, 1, G4);
  TILE(12, 0, 0, 2, 0, 1, G4);
  TILE(13, 1, 1, 0, 1, 1, G4);
  TILE(14, 2, 0, 1, 0, 0, G0);
  TILE(15, 0, 1, 2, 1, 0, NOG);

  __syncthreads();   // full drain before overlaying redbuf on lsA

  // ---- epilogue: per-row top-2 over this block's 256 columns (32-bit keys) ----
  int* red = (int*)&lsA[0][0];   // [4][256][2] i32 = 8 KB
  float c2v[4];
  int   colv[4];
  #pragma unroll
  for (int ni = 0; ni < 4; ++ni) {
    colv[ni] = bn * 256 + wn * 64 + ni * 16 + l15;
    c2v[ni]  = c2[colv[ni]];
  }

  #pragma unroll
  for (int mi = 0; mi < 8; ++mi) {
    #pragma unroll
    for (int r = 0; r < 4; ++r) {
      int a = packKey32(fmaf(-2.0f, acc[mi][0][r], c2v[0]), colv[0]);
      int b = packKey32(fmaf(-2.0f, acc[mi][1][r], c2v[1]), colv[1]);
      int c = packKey32(fmaf(-2.0f, acc[mi][2][r], c2v[2]), colv[2]);
      int d = packKey32(fmaf(-2.0f, acc[mi][3][r], c2v[3]), colv[3]);
      int lo1 = imin(a, b), hi1 = imax(a, b);
      int lo2 = imin(c, d), hi2 = imax(c, d);
      int k1 = imin(lo1, lo2);
      int k2 = imin(imax(lo1, lo2), imin(hi1, hi2));
      #pragma unroll
      for (int m = 1; m < 16; m <<= 1) {
        int o1 = __shfl_xor(k1, m);
        int o2 = __shfl_xor(k2, m);
        int n1 = imin(k1, o1);
        int n2 = imin(imax(k1, o1), imin(k2, o2));
        k1 = n1; k2 = n2;
      }
      if (l15 == 0) {
        int rl = wm * 128 + mi * 16 + kgrp * 4 + r;
        red[(wn * 256 + rl) * 2 + 0] = k1;
        red[(wn * 256 + rl) * 2 + 1] = k2;
      }
    }
  }
  __syncthreads();

  if (t < 256) {
    int k1 = red[(0 * 256 + t) * 2 + 0];
    int k2 = red[(0 * 256 + t) * 2 + 1];
    #pragma unroll
    for (int q = 1; q < 4; ++q) {
      int p1 = red[(q * 256 + t) * 2 + 0];
      int p2 = red[(q * 256 + t) * 2 + 1];
      int n1 = imin(k1, p1);
      int n2 = imin(imax(k1, p1), imin(k2, p2));
      k1 = n1; k2 = n2;
    }
    size_t o = (size_t)(bm * 256 + t) * 128 + (size_t)bn * 2;
    cand[o]     = k1;
    cand[o + 1] = k2;
  }
}

// ---------------- kernel 1 (fallback, known-good structure): on-the-fly bf16 128^2 ----------------
__global__ __launch_bounds__(256) void snap_gemm_slow(const float* __restrict__ x,
                                                      const float* __restrict__ cb,
                                                      const float* __restrict__ c2,
                                                      int* __restrict__ cand) {
  __shared__ ushort lsA[2][8192];
  __shared__ ushort lsB[2][8192];
  __shared__ int redbuf[2][128][2];

  const int t    = threadIdx.x;
  const int lane = t & 63;
  const int wid  = t >> 6;
  const int wm   = wid & 1;
  const int wn   = wid >> 1;
  const int l15  = lane & 15;
  const int kgrp = lane >> 4;

  const int bm = blockIdx.x & 127;
  const int bn = blockIdx.x >> 7;
  const int rowBase = bm * 128;
  const int colBase = bn * 128;

  const float* aptr[4];
  const float* bptr[4];
  int ldsOff[4];
  #pragma unroll
  for (int i = 0; i < 4; ++i) {
    int pc = t + 256 * i;
    int row = pc >> 3;
    int g = (pc & 7) ^ (row & 7);
    aptr[i] = x  + (size_t)(rowBase + row) * DIM + g * 8;
    bptr[i] = cb + (size_t)(colBase + row) * DIM + g * 8;
    ldsOff[i] = pc * 8;
  }

  f32x4 acc[4][4];
  #pragma unroll
  for (int mi = 0; mi < 4; ++mi)
    #pragma unroll
    for (int ni = 0; ni < 4; ++ni)
      acc[mi][ni] = (f32x4){0.f, 0.f, 0.f, 0.f};

  auto STAGE = [&](int buf, int kt) {
    const int kOff = kt * 64;
    #pragma unroll
    for (int i = 0; i < 4; ++i) {
      f32x4 a0 = *(const f32x4*)(aptr[i] + kOff);
      f32x4 a1 = *(const f32x4*)(aptr[i] + kOff + 4);
      f32x4 b0 = *(const f32x4*)(bptr[i] + kOff);
      f32x4 b1 = *(const f32x4*)(bptr[i] + kOff + 4);
      bf16x8 pa, pb;
      #pragma unroll
      for (int j = 0; j < 4; ++j) {
        pa[j]     = (short)f2bf(a0[j]);
        pa[j + 4] = (short)f2bf(a1[j]);
        pb[j]     = (short)f2bf(b0[j]);
        pb[j + 4] = (short)f2bf(b1[j]);
      }
      *(bf16x8*)(&lsA[buf][ldsOff[i]]) = pa;
      *(bf16x8*)(&lsB[buf][ldsOff[i]]) = pb;
    }
  };

  STAGE(0, 0);
  __syncthreads();

  for (int kt = 0; kt < DIM / 64; ++kt) {
    const int cur = kt & 1;
    if (kt < DIM / 64 - 1) STAGE(cur ^ 1, kt + 1);

    const ushort* bA = &lsA[cur][0];
    const ushort* bB = &lsB[cur][0];
    #pragma unroll
    for (int ks = 0; ks < 2; ++ks) {
      const int gidx = ks * 4 + kgrp;
      bf16x8 af[4], bfr[4];
      #pragma unroll
      for (int mi = 0; mi < 4; ++mi) {
        int r_ = wm * 64 + mi * 16 + l15;
        af[mi] = *(const bf16x8*)(bA + (r_ * 8 + (gidx ^ (r_ & 7))) * 8);
      }
      #pragma unroll
      for (int ni = 0; ni < 4; ++ni) {
        int c_ = wn * 64 + ni * 16 + l15;
        bfr[ni] = *(const bf16x8*)(bB + (c_ * 8 + (gidx ^ (c_ & 7))) * 8);
      }
      #pragma unroll
      for (int mi = 0; mi < 4; ++mi)
        #pragma unroll
        for (int ni = 0; ni < 4; ++ni)
          acc[mi][ni] = __builtin_amdgcn_mfma_f32_16x16x32_bf16(af[mi], bfr[ni], acc[mi][ni], 0, 0, 0);
    }
    __syncthreads();
  }

  float c2v[4];
  int   colv[4];
  #pragma unroll
  for (int ni = 0; ni < 4; ++ni) {
    colv[ni] = colBase + wn * 64 + ni * 16 + l15;
    c2v[ni]  = c2[colv[ni]];
  }

  #pragma unroll
  for (int mi = 0; mi < 4; ++mi) {
    #pragma unroll
    for (int r = 0; r < 4; ++r) {
      int a = packKey32(fmaf(-2.0f, acc[mi][0][r], c2v[0]), colv[0]);
      int b = packKey32(fmaf(-2.0f, acc[mi][1][r], c2v[1]), colv[1]);
      int c = packKey32(fmaf(-2.0f, acc[mi][2][r], c2v[2]), colv[2]);
      int d = packKey32(fmaf(-2.0f, acc[mi][3][r], c2v[3]), colv[3]);
      int lo1 = imin(a, b), hi1 = imax(a, b);
      int lo2 = imin(c, d), hi2 = imax(c, d);
      int k1 = imin(lo1, lo2);
      int k2 = imin(imax(lo1, lo2), imin(hi1, hi2));
      #pragma unroll
      for (int m = 1; m < 16; m <<= 1) {
        int o1 = __shfl_xor(k1, m);
        int o2 = __shfl_xor(k2, m);
        int n1 = imin(k1, o1);
        int n2 = imin(imax(k1, o1), imin(k2, o2));
        k1 = n1; k2 = n2;
      }
      if (l15 == 0) {
        int rl = wm * 64 + mi * 16 + kgrp * 4 + r;
        redbuf[wn][rl][0] = k1;
        redbuf[wn][rl][1] = k2;
      }
    }
  }
  __syncthreads();

  if (t < 128) {
    int a1 = redbuf[0][t][0], a2 = redbuf[0][t][1];
    int b1 = redbuf[1][t][0], b2 = redbuf[1][t][1];
    int m1 = imin(a1, b1);
    int m2 = imin(imax(a1, b1), imin(a2, b2));
    size_t o = (size_t)(rowBase + t) * 256 + (size_t)bn * 2;
    cand[o]     = m1;
    cand[o + 1] = m2;
  }
}

// ---------------- kernel 2: exact f64 rerank of candidates within margin of pool-min ----------------
__global__ __launch_bounds__(256) void rerank(const float* __restrict__ x,
                                              const float* __restrict__ cb,
                                              const int* __restrict__ cand,
                                              int* __restrict__ bestidx,
                                              int poolN) {
  const int row = blockIdx.x;
  const int t = threadIdx.x, lane = t & 63, wid = t >> 6;
  __shared__ int    smin[4];
  __shared__ int    gshared;
  __shared__ double dpart[4];
  __shared__ int    cnt;
  __shared__ int    list[64];

  int my = (t < poolN) ? cand[(size_t)row * poolN + t] : 0x7FFFFFFF;
  int k = my;
  #pragma unroll
  for (int off = 32; off; off >>= 1) k = imin(k, __shfl_down(k, off));
  if (lane == 0) smin[wid] = k;
  if (t == 0) cnt = 0;
  __syncthreads();
  if (t == 0) {
    int g = smin[0];
    for (int i = 1; i < 4; ++i) g = imin(g, smin[i]);
    gshared = g;
  }
  __syncthreads();

  const int gq = gshared >> 14;
  if ((my >> 14) <= gq + MARGIN_Q) {
    int p = atomicAdd(&cnt, 1);
    if (p < 64) list[p] = my & 16383;
  }
  __syncthreads();
  int n = cnt; if (n > 64) n = 64;

  uint64_t best = ~0ull;
  const float* xr = x + (size_t)row * DIM;
  for (int i = 0; i < n; ++i) {
    const int cidx = list[i];
    const float* cr = cb + (size_t)cidx * DIM;
    double p = 0.0;
    #pragma unroll
    for (int j = 0; j < 4; ++j) {
      int d = t + 256 * j;
      double diff = (double)xr[d] - (double)cr[d];
      p += diff * diff;
    }
    #pragma unroll
    for (int off = 32; off; off >>= 1) p += __shfl_down(p, off);
    if (lane == 0) dpart[wid] = p;
    __syncthreads();
    if (t == 0) {
      double d2 = dpart[0] + dpart[1] + dpart[2] + dpart[3];
      uint64_t bits = (uint64_t)__double_as_longlong(d2);
      uint64_t key = (bits & ~0x3FFFull) | (uint32_t)cidx;
      if (key < best) best = key;
    }
    __syncthreads();
  }
  if (t == 0) bestidx[row] = (int)(best & 0x3FFFull);
}

// ---------------- kernel 3: gather winning codebook rows ----------------
__global__ __launch_bounds__(256) void gather_rows(const float* __restrict__ cb,
                                                   const int* __restrict__ bestidx,
                                                   float* __restrict__ out) {
  const int row = blockIdx.x;
  const int idx = bestidx[row];
  f32x4 v = *(const f32x4*)(cb + (size_t)idx * DIM + threadIdx.x * 4);
  *(f32x4*)(out + (size_t)row * DIM + threadIdx.x * 4) = v;
}

extern "C" void kernel_launch(void* const* d_in, const int* in_sizes, int n_in,
                              void* d_out, int out_size, void* d_ws, size_t ws_size,
                              hipStream_t stream) {
  const float* x  = (const float*)d_in[0];
  const float* cb = (const float*)d_in[1];
  float* out = (float*)d_out;

  float* c2      = (float*)d_ws;                        // 64 KB
  int*   bestidx = (int*)((char*)d_ws + 64 * 1024);     // 64 KB

  const size_t candBytes = (size_t)NROWS * 128 * 4;     // 8 MB (32-bit keys)
  const size_t needFast  = 128 * 1024 + candBytes;

  c2_kernel<<<NCODES, 256, 0, stream>>>(cb, c2);

  if (ws_size >= needFast) {
    uchar* xs = (uchar*)d_out;                          // 16.8 MB fp8, tile-blocked+swizzled
    uchar* cs = xs + (size_t)NROWS * DIM;               // 16.8 MB
    int* cand = (int*)((char*)d_ws + 128 * 1024);

    convert_fp8_swz<<<4096, 256, 0, stream>>>(x,  xs);
    convert_fp8_swz<<<4096, 256, 0, stream>>>(cb, cs);
    snap_gemm256<<<4096, 512, 0, stream>>>(xs, cs, c2, cand);
    rerank<<<NROWS, 256, 0, stream>>>(x, cb, cand, bestidx, 128);
    gather_rows<<<NROWS, 256, 0, stream>>>(cb, bestidx, out);
  } else {
    int* cand = (int*)d_out;
    snap_gemm_slow<<<(NROWS / 128) * (NCODES / 128), 256, 0, stream>>>(x, cb, c2, cand);
    rerank<<<NROWS, 256, 0, stream>>>(x, cb, cand, bestidx, 256);
    gather_rows<<<NROWS, 256, 0, stream>>>(cb, bestidx, out);
  }
}

// Round 10
// 591.853 us; speedup vs baseline: 1.3871x; 1.0901x over previous
//
#include <hip/hip_runtime.h>
#include <hip/hip_bf16.h>
#include <hip/hip_fp8.h>
#include <stdint.h>

// x: (4,4096,1024) f32 -> 16384 x 1024 rows; codebook: (16384,1024) f32
#define NROWS  16384
#define NCODES 16384
#define DIM    1024
#define NT     16           // DIM / BK,  BK = 64
#define MARGIN_Q 514        // fp8 path: 32.1 in 1/16 units (~10 sigma of fp8 score noise)

typedef float f32x4  __attribute__((ext_vector_type(4)));
typedef short bf16x8 __attribute__((ext_vector_type(8)));
typedef long  longx2 __attribute__((ext_vector_type(2)));
typedef unsigned char uchar;

__device__ __forceinline__ ushort f2bf(float f) {
  uint32_t u = __float_as_uint(f);
  uint32_t r = u + 0x7FFFu + ((u >> 16) & 1u);
  return (ushort)(r >> 16);
}
__device__ __forceinline__ int imin(int a, int b){ return a < b ? a : b; }
__device__ __forceinline__ int imax(int a, int b){ return a < b ? b : a; }
__device__ __forceinline__ int packKey32(float s, int idx) {
  int q = (int)rintf(s * 16.0f);
  return q * 16384 + idx;
}

#define GLDS16(gp, lp) \
  __builtin_amdgcn_global_load_lds((const __attribute__((address_space(1))) void*)(gp), \
                                   (__attribute__((address_space(3))) void*)(lp), 16, 0, 0)

__device__ __forceinline__ void sbar() {
  asm volatile("" ::: "memory");
  __builtin_amdgcn_s_barrier();
  asm volatile("" ::: "memory");
}

// ---------------- kernel 0: c2[c] = sum(codebook[c]^2) (exact f32) ----------------
__global__ __launch_bounds__(256) void c2_kernel(const float* __restrict__ cb,
                                                 float* __restrict__ c2) {
  const int code = blockIdx.x;
  const int t = threadIdx.x, lane = t & 63, wid = t >> 6;
  f32x4 v = *(const f32x4*)(cb + (size_t)code * DIM + t * 4);
  float s = v[0]*v[0] + v[1]*v[1] + v[2]*v[2] + v[3]*v[3];
  #pragma unroll
  for (int off = 32; off; off >>= 1) s += __shfl_down(s, off);
  __shared__ float part[4];
  if (lane == 0) part[wid] = s;
  __syncthreads();
  if (t == 0) c2[code] = part[0] + part[1] + part[2] + part[3];
}

// ---------------- kernel 0b: f32 -> fp8 e4m3, paired-slot 256x64-tile layout ----------------
// Tile (m,kt) = 16 KB: 256 rows x 64 k-bytes. Row = 4 x 16B pairs. Logical pair q
// holds k-slots (q, q+4) (bytes q*8..+7 and q*8+32..+39) — exactly one lane's
// (ks=0, ks=1) fragment pair. Phys position p = q ^ ((row>>1)&3) (bank swizzle).
__global__ __launch_bounds__(256) void convert_fp8_pair(const float* __restrict__ src,
                                                        uchar* __restrict__ dst) {
  const int chunk = blockIdx.x * 256 + threadIdx.x;   // [0, 2^20)
  const int p   = chunk & 3;
  const int row = (chunk >> 2) & 255;
  const int kt  = (chunk >> 10) & 15;
  const int m   = chunk >> 14;
  const int q   = p ^ ((row >> 1) & 3);
  const float* s = src + (size_t)(m * 256 + row) * DIM + kt * 64 + q * 8;
  uint64_t lo = 0, hi = 0;
  #pragma unroll
  for (int j = 0; j < 8; ++j) {
    __hip_fp8_e4m3 a(s[j]);        // k-slot q      (ks = 0)
    __hip_fp8_e4m3 b(s[j + 32]);   // k-slot q + 4  (ks = 1)
    lo |= (uint64_t)a.__x << (8 * j);
    hi |= (uint64_t)b.__x << (8 * j);
  }
  uint64_t* o = (uint64_t*)(dst + (size_t)chunk * 16);
  o[0] = lo; o[1] = hi;
}

// ---------------- kernel 1: 256^2 fp8 MFMA GEMM, 1-barrier/K-tile, 2 blocks/CU ----------------
// Read: one ds_read_b128 per fragment-pair at row*64 + (kgrp^((l15>>1)&3))*16
// (+ mi*1024 imm). Uniform 2-way bank pattern (free). 12 b128 per wave/K-tile.

#define STAGE_A(BUF, KT) do {                                                     \
    GLDS16(ga + (KT)*16384,        &lsA[BUF][w*1024]);                            \
    GLDS16(ga + (KT)*16384 + 8192, &lsA[BUF][w*1024 + 8192]);                     \
  } while (0)
#define STAGE_B(BUF, KT) do {                                                     \
    GLDS16(gb + (KT)*16384,        &lsB[BUF][w*1024]);                            \
    GLDS16(gb + (KT)*16384 + 8192, &lsB[BUF][w*1024 + 8192]);                     \
  } while (0)

#define RD_A(MIB, BUF) do {                                                       \
    _Pragma("unroll")                                                             \
    for (int mi_ = 0; mi_ < 4; ++mi_) {                                           \
      longx2 v_ = *(const longx2*)(Apos[BUF] + ((MIB) + mi_) * 1024);             \
      aF[mi_][0] = v_[0]; aF[mi_][1] = v_[1];                                     \
    } } while (0)
#define RD_B(BUF) do {                                                            \
    _Pragma("unroll")                                                             \
    for (int ni_ = 0; ni_ < 4; ++ni_) {                                           \
      longx2 v_ = *(const longx2*)(Bpos[BUF] + ni_ * 1024);                       \
      bF[ni_][0] = v_[0]; bF[ni_][1] = v_[1];                                     \
    } } while (0)

#define MMA_Q(MB, NB) do {                                                        \
    __builtin_amdgcn_s_setprio(1);                                                \
    _Pragma("unroll")                                                             \
    for (int ks_ = 0; ks_ < 2; ++ks_) {                                           \
      _Pragma("unroll")                                                           \
      for (int mi_ = 0; mi_ < 4; ++mi_) {                                         \
        _Pragma("unroll")                                                         \
        for (int ni_ = 0; ni_ < 2; ++ni_)                                         \
          acc[(MB) + mi_][(NB) + ni_] = __builtin_amdgcn_mfma_f32_16x16x32_fp8_fp8( \
              aF[mi_][ks_], bF[(NB) + ni_][ks_], acc[(MB) + mi_][(NB) + ni_], 0, 0, 0); \
      } }                                                                         \
    __builtin_amdgcn_s_setprio(0);                                                \
  } while (0)

#define G0  asm volatile("s_waitcnt vmcnt(0)" ::: "memory")
#define NOG do {} while (0)

// One K-tile, ONE barrier. Stage(t+1) targets the buffers whose reads drained
// before the PREVIOUS barrier (2-deep alternation) -> no intra-tile hazard.
// End-of-tile: lgkm(0) (reads in regs) + vmcnt guard (stage landed) + barrier.
#define TILE(KT, CUR, NXT, DOST, GUARD) do {                                      \
    if (DOST) { STAGE_A(NXT, (KT) + 1); STAGE_B(NXT, (KT) + 1); }                 \
    RD_B(CUR);                                                                    \
    RD_A(0, CUR);                                                                 \
    MMA_Q(0, 0); MMA_Q(0, 2);                                                     \
    RD_A(4, CUR);                                                                 \
    MMA_Q(4, 0); MMA_Q(4, 2);                                                     \
    asm volatile("s_waitcnt lgkmcnt(0)" ::: "memory");                            \
    GUARD;                                                                        \
    sbar();                                                                       \
  } while (0)

__global__ __launch_bounds__(512, 2) void snap_gemm256(const uchar* __restrict__ xs,
                                                       const uchar* __restrict__ cs,
                                                       const float* __restrict__ c2,
                                                       int* __restrict__ cand) {
  __shared__ uchar lsA[2][16384];   // 2-deep A (32 KB)
  __shared__ uchar lsB[2][16384];   // 2-deep B (32 KB) -> 64 KB total, 2 blocks/CU

  const int t    = threadIdx.x;
  const int lane = t & 63;
  const int w    = t >> 6;          // 0..7
  const int wm   = w >> 2;          // 0..1
  const int wn   = w & 3;           // 0..3
  const int l15  = lane & 15;
  const int kgrp = lane >> 4;

  // XCD-aware swizzle (bijective: 4096 % 8 == 0)
  const int bid = blockIdx.x;
  const int swz = (bid & 7) * 512 + (bid >> 3);
  const int bm  = swz & 63;
  const int bn  = swz >> 6;

  const uchar* ga = xs + (size_t)bm * 16 * 16384 + w * 1024 + lane * 16;
  const uchar* gb = cs + (size_t)bn * 16 * 16384 + w * 1024 + lane * 16;

  // Precomputed LDS read base pointers (bytes). Pair position depends only on
  // kgrp and row bits 1-2 (= l15 bits 1-2) -> uniform across mi/ni.
  const int posoff = (kgrp ^ ((l15 >> 1) & 3)) * 16;
  const int arow   = (wm * 128 + l15) * 64;
  const int brow   = (wn * 64  + l15) * 64;
  const uchar* Apos[2]; const uchar* Bpos[2];
  #pragma unroll
  for (int b = 0; b < 2; ++b) { Apos[b] = &lsA[b][arow + posoff]; Bpos[b] = &lsB[b][brow + posoff]; }

  f32x4 acc[8][4];
  #pragma unroll
  for (int mi = 0; mi < 8; ++mi)
    #pragma unroll
    for (int ni = 0; ni < 4; ++ni)
      acc[mi][ni] = (f32x4){0.f, 0.f, 0.f, 0.f};

  long aF[4][2], bF[4][2];

  // ---- prologue: tile 0 (4 loads) ----
  STAGE_A(0, 0); STAGE_B(0, 0);
  G0;
  sbar();

  // Fully unrolled: CUR = kt&1, NXT = (kt+1)&1; stage 1 tile ahead at tile start.
  TILE(0 , 0, 1, 1, G0);
  TILE(1 , 1, 0, 1, G0);
  TILE(2 , 0, 1, 1, G0);
  TILE(3 , 1, 0, 1, G0);
  TILE(4 , 0, 1, 1, G0);
  TILE(5 , 1, 0, 1, G0);
  TILE(6 , 0, 1, 1, G0);
  TILE(7 , 1, 0, 1, G0);
  TILE(8 , 0, 1, 1, G0);
  TILE(9 , 1, 0, 1, G0);
  TILE(10, 0, 1, 1, G0);
  TILE(11, 1, 0, 1, G0);
  TILE(12, 0, 1, 1, G0);
  TILE(13, 1, 0, 1, G0);
  TILE(14, 0, 1, 1, G0);
  TILE(15, 1, 0, 0, NOG);

  __syncthreads();   // full drain before overlaying redbuf on lsA

  // ---- epilogue: per-row top-2 over this block's 256 columns (32-bit keys) ----
  int* red = (int*)&lsA[0][0];   // [4][256][2] i32 = 8 KB
  float c2v[4];
  int   colv[4];
  #pragma unroll
  for (int ni = 0; ni < 4; ++ni) {
    colv[ni] = bn * 256 + wn * 64 + ni * 16 + l15;
    c2v[ni]  = c2[colv[ni]];
  }

  #pragma unroll
  for (int mi = 0; mi < 8; ++mi) {
    #pragma unroll
    for (int r = 0; r < 4; ++r) {
      int a = packKey32(fmaf(-2.0f, acc[mi][0][r], c2v[0]), colv[0]);
      int b = packKey32(fmaf(-2.0f, acc[mi][1][r], c2v[1]), colv[1]);
      int c = packKey32(fmaf(-2.0f, acc[mi][2][r], c2v[2]), colv[2]);
      int d = packKey32(fmaf(-2.0f, acc[mi][3][r], c2v[3]), colv[3]);
      int lo1 = imin(a, b), hi1 = imax(a, b);
      int lo2 = imin(c, d), hi2 = imax(c, d);
      int k1 = imin(lo1, lo2);
      int k2 = imin(imax(lo1, lo2), imin(hi1, hi2));
      #pragma unroll
      for (int m = 1; m < 16; m <<= 1) {
        int o1 = __shfl_xor(k1, m);
        int o2 = __shfl_xor(k2, m);
        int n1 = imin(k1, o1);
        int n2 = imin(imax(k1, o1), imin(k2, o2));
        k1 = n1; k2 = n2;
      }
      if (l15 == 0) {
        int rl = wm * 128 + mi * 16 + kgrp * 4 + r;
        red[(wn * 256 + rl) * 2 + 0] = k1;
        red[(wn * 256 + rl) * 2 + 1] = k2;
      }
    }
  }
  __syncthreads();

  if (t < 256) {
    int k1 = red[(0 * 256 + t) * 2 + 0];
    int k2 = red[(0 * 256 + t) * 2 + 1];
    #pragma unroll
    for (int q = 1; q < 4; ++q) {
      int p1 = red[(q * 256 + t) * 2 + 0];
      int p2 = red[(q * 256 + t) * 2 + 1];
      int n1 = imin(k1, p1);
      int n2 = imin(imax(k1, p1), imin(k2, p2));
      k1 = n1; k2 = n2;
    }
    size_t o = (size_t)(bm * 256 + t) * 128 + (size_t)bn * 2;
    cand[o]     = k1;
    cand[o + 1] = k2;
  }
}

// ---------------- kernel 1 (fallback, known-good structure): on-the-fly bf16 128^2 ----------------
__global__ __launch_bounds__(256) void snap_gemm_slow(const float* __restrict__ x,
                                                      const float* __restrict__ cb,
                                                      const float* __restrict__ c2,
                                                      int* __restrict__ cand) {
  __shared__ ushort lsA[2][8192];
  __shared__ ushort lsB[2][8192];
  __shared__ int redbuf[2][128][2];

  const int t    = threadIdx.x;
  const int lane = t & 63;
  const int wid  = t >> 6;
  const int wm   = wid & 1;
  const int wn   = wid >> 1;
  const int l15  = lane & 15;
  const int kgrp = lane >> 4;

  const int bm = blockIdx.x & 127;
  const int bn = blockIdx.x >> 7;
  const int rowBase = bm * 128;
  const int colBase = bn * 128;

  const float* aptr[4];
  const float* bptr[4];
  int ldsOff[4];
  #pragma unroll
  for (int i = 0; i < 4; ++i) {
    int pc = t + 256 * i;
    int row = pc >> 3;
    int g = (pc & 7) ^ (row & 7);
    aptr[i] = x  + (size_t)(rowBase + row) * DIM + g * 8;
    bptr[i] = cb + (size_t)(colBase + row) * DIM + g * 8;
    ldsOff[i] = pc * 8;
  }

  f32x4 acc[4][4];
  #pragma unroll
  for (int mi = 0; mi < 4; ++mi)
    #pragma unroll
    for (int ni = 0; ni < 4; ++ni)
      acc[mi][ni] = (f32x4){0.f, 0.f, 0.f, 0.f};

  auto STAGE = [&](int buf, int kt) {
    const int kOff = kt * 64;
    #pragma unroll
    for (int i = 0; i < 4; ++i) {
      f32x4 a0 = *(const f32x4*)(aptr[i] + kOff);
      f32x4 a1 = *(const f32x4*)(aptr[i] + kOff + 4);
      f32x4 b0 = *(const f32x4*)(bptr[i] + kOff);
      f32x4 b1 = *(const f32x4*)(bptr[i] + kOff + 4);
      bf16x8 pa, pb;
      #pragma unroll
      for (int j = 0; j < 4; ++j) {
        pa[j]     = (short)f2bf(a0[j]);
        pa[j + 4] = (short)f2bf(a1[j]);
        pb[j]     = (short)f2bf(b0[j]);
        pb[j + 4] = (short)f2bf(b1[j]);
      }
      *(bf16x8*)(&lsA[buf][ldsOff[i]]) = pa;
      *(bf16x8*)(&lsB[buf][ldsOff[i]]) = pb;
    }
  };

  STAGE(0, 0);
  __syncthreads();

  for (int kt = 0; kt < DIM / 64; ++kt) {
    const int cur = kt & 1;
    if (kt < DIM / 64 - 1) STAGE(cur ^ 1, kt + 1);

    const ushort* bA = &lsA[cur][0];
    const ushort* bB = &lsB[cur][0];
    #pragma unroll
    for (int ks = 0; ks < 2; ++ks) {
      const int gidx = ks * 4 + kgrp;
      bf16x8 af[4], bfr[4];
      #pragma unroll
      for (int mi = 0; mi < 4; ++mi) {
        int r_ = wm * 64 + mi * 16 + l15;
        af[mi] = *(const bf16x8*)(bA + (r_ * 8 + (gidx ^ (r_ & 7))) * 8);
      }
      #pragma unroll
      for (int ni = 0; ni < 4; ++ni) {
        int c_ = wn * 64 + ni * 16 + l15;
        bfr[ni] = *(const bf16x8*)(bB + (c_ * 8 + (gidx ^ (c_ & 7))) * 8);
      }
      #pragma unroll
      for (int mi = 0; mi < 4; ++mi)
        #pragma unroll
        for (int ni = 0; ni < 4; ++ni)
          acc[mi][ni] = __builtin_amdgcn_mfma_f32_16x16x32_bf16(af[mi], bfr[ni], acc[mi][ni], 0, 0, 0);
    }
    __syncthreads();
  }

  float c2v[4];
  int   colv[4];
  #pragma unroll
  for (int ni = 0; ni < 4; ++ni) {
    colv[ni] = colBase + wn * 64 + ni * 16 + l15;
    c2v[ni]  = c2[colv[ni]];
  }

  #pragma unroll
  for (int mi = 0; mi < 4; ++mi) {
    #pragma unroll
    for (int r = 0; r < 4; ++r) {
      int a = packKey32(fmaf(-2.0f, acc[mi][0][r], c2v[0]), colv[0]);
      int b = packKey32(fmaf(-2.0f, acc[mi][1][r], c2v[1]), colv[1]);
      int c = packKey32(fmaf(-2.0f, acc[mi][2][r], c2v[2]), colv[2]);
      int d = packKey32(fmaf(-2.0f, acc[mi][3][r], c2v[3]), colv[3]);
      int lo1 = imin(a, b), hi1 = imax(a, b);
      int lo2 = imin(c, d), hi2 = imax(c, d);
      int k1 = imin(lo1, lo2);
      int k2 = imin(imax(lo1, lo2), imin(hi1, hi2));
      #pragma unroll
      for (int m = 1; m < 16; m <<= 1) {
        int o1 = __shfl_xor(k1, m);
        int o2 = __shfl_xor(k2, m);
        int n1 = imin(k1, o1);
        int n2 = imin(imax(k1, o1), imin(k2, o2));
        k1 = n1; k2 = n2;
      }
      if (l15 == 0) {
        int rl = wm * 64 + mi * 16 + kgrp * 4 + r;
        redbuf[wn][rl][0] = k1;
        redbuf[wn][rl][1] = k2;
      }
    }
  }
  __syncthreads();

  if (t < 128) {
    int a1 = redbuf[0][t][0], a2 = redbuf[0][t][1];
    int b1 = redbuf[1][t][0], b2 = redbuf[1][t][1];
    int m1 = imin(a1, b1);
    int m2 = imin(imax(a1, b1), imin(a2, b2));
    size_t o = (size_t)(rowBase + t) * 256 + (size_t)bn * 2;
    cand[o]     = m1;
    cand[o + 1] = m2;
  }
}

// ---------------- kernel 2: exact f64 rerank of candidates within margin of pool-min ----------------
__global__ __launch_bounds__(256) void rerank(const float* __restrict__ x,
                                              const float* __restrict__ cb,
                                              const int* __restrict__ cand,
                                              int* __restrict__ bestidx,
                                              int poolN) {
  const int row = blockIdx.x;
  const int t = threadIdx.x, lane = t & 63, wid = t >> 6;
  __shared__ int    smin[4];
  __shared__ int    gshared;
  __shared__ double dpart[4];
  __shared__ int    cnt;
  __shared__ int    list[64];

  int my = (t < poolN) ? cand[(size_t)row * poolN + t] : 0x7FFFFFFF;
  int k = my;
  #pragma unroll
  for (int off = 32; off; off >>= 1) k = imin(k, __shfl_down(k, off));
  if (lane == 0) smin[wid] = k;
  if (t == 0) cnt = 0;
  __syncthreads();
  if (t == 0) {
    int g = smin[0];
    for (int i = 1; i < 4; ++i) g = imin(g, smin[i]);
    gshared = g;
  }
  __syncthreads();

  const int gq = gshared >> 14;
  if ((my >> 14) <= gq + MARGIN_Q) {
    int p = atomicAdd(&cnt, 1);
    if (p < 64) list[p] = my & 16383;
  }
  __syncthreads();
  int n = cnt; if (n > 64) n = 64;

  uint64_t best = ~0ull;
  const float* xr = x + (size_t)row * DIM;
  for (int i = 0; i < n; ++i) {
    const int cidx = list[i];
    const float* cr = cb + (size_t)cidx * DIM;
    double p = 0.0;
    #pragma unroll
    for (int j = 0; j < 4; ++j) {
      int d = t + 256 * j;
      double diff = (double)xr[d] - (double)cr[d];
      p += diff * diff;
    }
    #pragma unroll
    for (int off = 32; off; off >>= 1) p += __shfl_down(p, off);
    if (lane == 0) dpart[wid] = p;
    __syncthreads();
    if (t == 0) {
      double d2 = dpart[0] + dpart[1] + dpart[2] + dpart[3];
      uint64_t bits = (uint64_t)__double_as_longlong(d2);
      uint64_t key = (bits & ~0x3FFFull) | (uint32_t)cidx;
      if (key < best) best = key;
    }
    __syncthreads();
  }
  if (t == 0) bestidx[row] = (int)(best & 0x3FFFull);
}

// ---------------- kernel 3: gather winning codebook rows ----------------
__global__ __launch_bounds__(256) void gather_rows(const float* __restrict__ cb,
                                                   const int* __restrict__ bestidx,
                                                   float* __restrict__ out) {
  const int row = blockIdx.x;
  const int idx = bestidx[row];
  f32x4 v = *(const f32x4*)(cb + (size_t)idx * DIM + threadIdx.x * 4);
  *(f32x4*)(out + (size_t)row * DIM + threadIdx.x * 4) = v;
}

extern "C" void kernel_launch(void* const* d_in, const int* in_sizes, int n_in,
                              void* d_out, int out_size, void* d_ws, size_t ws_size,
                              hipStream_t stream) {
  const float* x  = (const float*)d_in[0];
  const float* cb = (const float*)d_in[1];
  float* out = (float*)d_out;

  float* c2      = (float*)d_ws;                        // 64 KB
  int*   bestidx = (int*)((char*)d_ws + 64 * 1024);     // 64 KB

  const size_t candBytes = (size_t)NROWS * 128 * 4;     // 8 MB (32-bit keys)
  const size_t needFast  = 128 * 1024 + candBytes;

  c2_kernel<<<NCODES, 256, 0, stream>>>(cb, c2);

  if (ws_size >= needFast) {
    uchar* xs = (uchar*)d_out;                          // 16.8 MB fp8, paired+swizzled
    uchar* cs = xs + (size_t)NROWS * DIM;               // 16.8 MB
    int* cand = (int*)((char*)d_ws + 128 * 1024);

    convert_fp8_pair<<<4096, 256, 0, stream>>>(x,  xs);
    convert_fp8_pair<<<4096, 256, 0, stream>>>(cb, cs);
    snap_gemm256<<<4096, 512, 0, stream>>>(xs, cs, c2, cand);
    rerank<<<NROWS, 256, 0, stream>>>(x, cb, cand, bestidx, 128);
    gather_rows<<<NROWS, 256, 0, stream>>>(cb, bestidx, out);
  } else {
    int* cand = (int*)d_out;
    snap_gemm_slow<<<(NROWS / 128) * (NCODES / 128), 256, 0, stream>>>(x, cb, c2, cand);
    rerank<<<NROWS, 256, 0, stream>>>(x, cb, cand, bestidx, 256);
    gather_rows<<<NROWS, 256, 0, stream>>>(cb, bestidx, out);
  }
}